// Round 12
// baseline (1075.639 us; speedup 1.0000x reference)
//
#include <hip/hip_runtime.h>
#include <math.h>

// Relational Network fused pipeline for MI355X (gfx950).
// B=32, D=64, K=26, QST=256, G=[512x6, 28], AGG at layer 4.
//
// Round 17 changes vs round 16:
//  - Register endgame: launch_bounds 2nd arg = min waves/EU; 8-wave blocks
//    clamp at 2 -> total cap 256/wave (explains R15===R13). M=128 spilled
//    because the compiler keeps acc in ARCH VGPRs (VGPR-form MFMA default
//    on gfx950) and never emits AGPR-form. R16's empty-asm "+a" pin only
//    ADDED copies (524us). FIX: issue the MFMA itself as inline asm with
//    the accumulator constrained "a" -> AGPR-form MFMA, acc lives in AGPRs
//    with ZERO loop copies. Arch = A(32)+X/Y(32)+addr ~85 <= 128,
//    AGPR = 128, total 213 <= 256. M=128 fits for the first time.
//  - k_prep vectorized: 8 bf16 (or 4 f32) per thread, single 16B stores
//    (was per-element 2B scatter).
//  - Structure otherwise = round 13 (M=128 tile, rolling-A + X/Y B
//    ping-pong, fenced epilogues, launch_bounds(512,2), grid 1024).

typedef __attribute__((ext_vector_type(8))) short bf16x8;   // 8 bf16 in 4 VGPRs
typedef __attribute__((ext_vector_type(4))) float f32x4;    // MFMA 16x16 accumulator
typedef __attribute__((ext_vector_type(4))) unsigned int u32x4;

__device__ __forceinline__ unsigned short f2bf(float f) {
    union { float f; unsigned u; } x; x.f = f;
    unsigned r = x.u + 0x7fffu + ((x.u >> 16) & 1u);   // RNE
    return (unsigned short)(r >> 16);
}

// ---------------- pack / transpose weights (vectorized) ----------------
// Wp layout per layer: [wave(8)][s(16)][jj(4)][lane(64)][j(8)] bf16,
//   value = W[n][k], n = (wave*4+jj)*16 + (lane&15), k = s*32 + (lane>>4)*8 + j.
// W0p: same with s(2) over padded K=64 (k >= 52 -> 0).
// W4v/W5v: fp32 [k/4][512 out][4] so k_tail threads stream float4.
// Each thread: one contiguous-granule 16B store (j- or k&3-innermost).
#define NPV_WP   98304            // 3 * 512 * 64   (8 bf16/thread)
#define NPV_W0P  4096             // 512 * 8        (8 bf16/thread)
#define NPV_W4   98304            // 768*512/4      (4 f32/thread)
#define NPV_W5   65536            // 512*512/4
#define NPV_TOTAL (NPV_WP + NPV_W0P + NPV_W4 + NPV_W5)   // 266240 = 1040*256
__global__ void k_prep(const float* __restrict__ W1, const float* __restrict__ W2,
                       const float* __restrict__ W3, const float* __restrict__ W0,
                       const float* __restrict__ W4, const float* __restrict__ W5,
                       unsigned short* __restrict__ Wp,   // [3][262144] bf16
                       unsigned short* __restrict__ W0p,  // [32768] bf16
                       float* __restrict__ W4v,           // [192][512][4] fp32
                       float* __restrict__ W5v)           // [128][512][4] fp32
{
    int f = blockIdx.x * 256 + threadIdx.x;
    if (f < NPV_WP) {
        int l = f >> 15, r = f & 32767;
        int n = r >> 6, kq = r & 63;                 // k0 = kq*8
        const float* W = (l == 0) ? W1 : (l == 1) ? W2 : W3;
        const float* src = W + n * 512 + kq * 8;     // wave reads 2KB contiguous
        int s = kq >> 2, q4 = kq & 3;
        int wv = n >> 6, jj = (n >> 4) & 3, i16 = n & 15;
        int lane = q4 * 16 + i16;
        unsigned w[4];
        #pragma unroll
        for (int h = 0; h < 4; ++h)
            w[h] = (unsigned)f2bf(src[h * 2]) | ((unsigned)f2bf(src[h * 2 + 1]) << 16);
        *(u32x4*)(Wp + (size_t)l * 262144 + ((((wv * 16 + s) * 4 + jj) * 64 + lane) << 3))
            = (u32x4){w[0], w[1], w[2], w[3]};
    } else if (f < NPV_WP + NPV_W0P) {
        int g = f - NPV_WP;
        int n = g >> 3, kq = g & 7;
        int s = kq >> 2, q4 = kq & 3;
        int wv = n >> 6, jj = (n >> 4) & 3, i16 = n & 15;
        int lane = q4 * 16 + i16;
        unsigned w[4];
        #pragma unroll
        for (int h = 0; h < 4; ++h) {
            int k0 = kq * 8 + h * 2, k1 = k0 + 1;
            float f0 = (k0 < 52) ? W0[n * 52 + k0] : 0.f;
            float f1 = (k1 < 52) ? W0[n * 52 + k1] : 0.f;
            w[h] = (unsigned)f2bf(f0) | ((unsigned)f2bf(f1) << 16);
        }
        *(u32x4*)(W0p + ((((wv * 2 + s) * 4 + jj) * 64 + lane) << 3))
            = (u32x4){w[0], w[1], w[2], w[3]};
    } else if (f < NPV_WP + NPV_W0P + NPV_W4) {
        int g = f - (NPV_WP + NPV_W0P);
        int o = g / 192, kb = g % 192;
        float4 w = *(const float4*)(W4 + (size_t)o * 768 + kb * 4);   // coalesced
        *(float4*)(W4v + (size_t)kb * 2048 + o * 4) = w;
    } else {
        int g = f - (NPV_WP + NPV_W0P + NPV_W4);
        int o = g >> 7, kb = g & 127;
        float4 w = *(const float4*)(W5 + (size_t)o * 512 + kb * 4);   // coalesced
        *(float4*)(W5v + (size_t)kb * 2048 + o * 4) = w;
    }
}

// ---------------- h-store epilogue: bias + relu + bf16 LDS write ----
// Granule-column-major (128-row): byte = (col>>3)*2048 + ((row^((col>>3)&7)))*16
//                                       + (col&7)*2.
// DPP quad_perm swap on f32, then v_cvt_pk_bf16_f32 packs (col, col+1) into
// one dword; even lanes write ds_write_b32.
// sched_barrier(0) per mt-group caps the accvgpr-read batch.
__device__ __forceinline__ void store_h(const f32x4 (&acc)[8][4], const float* __restrict__ bl,
                                        unsigned short* hsm, int wave, int i16, int q4, int lane)
{
    char* base = (char*)hsm;
    #pragma unroll
    for (int j = 0; j < 4; ++j) {
        int col = (wave * 4 + j) * 16 + i16;
        int g = col >> 3;
        int e = g & 7;
        float bb = bl[col];
        char* colbase = base + g * 2048 + ((col & 7) << 1);
        #pragma unroll
        for (int mt = 0; mt < 8; ++mt) {
            #pragma unroll
            for (int r = 0; r < 4; ++r) {
                int row = mt * 16 + q4 * 4 + r;
                float v = fmaxf(acc[mt][j][r] + bb, 0.f);
                int vi = __float_as_int(v);
                // quad_perm [1,0,3,2]: each lane gets partner (lane^1)'s f32
                int swi = __builtin_amdgcn_update_dpp(0, vi, 0xB1, 0xF, 0xF, true);
                if ((lane & 1) == 0) {
                    unsigned pk;
                    asm("v_cvt_pk_bf16_f32 %0, %1, %2" : "=v"(pk) : "v"(vi), "v"(swi));
                    int slot = row ^ e;
                    *(unsigned*)(colbase + slot * 16) = pk;
                }
            }
            __builtin_amdgcn_sched_barrier(0);   // cap live acc-read transients
        }
    }
}

// AGPR-form MFMA: accumulator constrained to AGPR class at the instruction.
// This is the decisive mechanism: the builtin emits VGPR-form (acc in arch
// VGPRs -> 206-reg arch demand -> spill); this keeps acc in AGPRs with zero
// loop copies. D and C are the same tied "+a" quad.
#define MFMA_A(accv, av, bv) \
    asm volatile("v_mfma_f32_16x16x32_bf16 %0, %1, %2, %0" : "+a"(accv) : "v"(av), "v"(bv))

// mt-cluster: 4 MFMAs (j=0..3) consuming one A fragment + the 4 live B frags.
#define CLUSTER(AV, B0v, B1v, B2v, B3v, MT)   \
    __builtin_amdgcn_s_setprio(1);            \
    MFMA_A(acc[MT][0], AV, B0v);              \
    MFMA_A(acc[MT][1], AV, B1v);              \
    MFMA_A(acc[MT][2], AV, B2v);              \
    MFMA_A(acc[MT][3], AV, B3v);              \
    __builtin_amdgcn_s_setprio(0);            \
    __builtin_amdgcn_sched_barrier(0);

// ---------------- fused layers 0..3 ----------------
// One block per (b, p-pair): 128 pair-rows (rows 0-63: p0, 64-127: p1).
// h tile 128x512 bf16 in LDS, granule-column-major:
//   hsm[g=col>>3][slot=row^(g&7)][8 shorts], column stride 2048 B.
// 8 waves; wave w computes cols [w*64, w*64+64): acc = 8 (row tiles) x 4 (col tiles).
__global__ __launch_bounds__(512, 2) void k_fused(
    const float* __restrict__ x,
    const unsigned short* __restrict__ Wp,
    const unsigned short* __restrict__ W0p,
    const float* __restrict__ b0, const float* __restrict__ b1,
    const float* __restrict__ b2, const float* __restrict__ b3,
    float* __restrict__ P)
{
    __shared__ __align__(16) unsigned short hsm[128 * 512];   // 128 KiB
    __shared__ __align__(16) unsigned short xs[8 * 128 * 8];  // 16 KiB (x-pair tile)
    int t = threadIdx.x;
    int blk = blockIdx.x;
    int b = blk >> 5, pw = blk & 31;      // p0 = 2*pw, p1 = 2*pw+1

    // ---- stage xs: [g(8)][slot=row^g][8] bf16 of [x[b,q,:26] | x[b,p,:26] | 0],
    //      rows 0-63 -> p0, rows 64-127 -> p1; 4 threads per row ----
    {
        int row = t >> 2, sub = t & 3;
        int q = row & 63;
        int pp = (pw << 1) + (row >> 6);
        const float* xq = x + (size_t)(b * 64 + q) * 26;
        const float* xp = x + (size_t)(b * 64 + pp) * 26;
        #pragma unroll
        for (int gi = 0; gi < 2; ++gi) {
            int g = sub * 2 + gi;
            unsigned w[4];
            #pragma unroll
            for (int h = 0; h < 4; ++h) {
                int k0 = g * 8 + h * 2;
                int k1 = k0 + 1;
                float f0 = (k0 < 26) ? xq[k0] : (k0 < 52 ? xp[k0 - 26] : 0.f);
                float f1 = (k1 < 26) ? xq[k1] : (k1 < 52 ? xp[k1 - 26] : 0.f);
                w[h] = (unsigned)f2bf(f0) | ((unsigned)f2bf(f1) << 16);
            }
            *(u32x4*)((char*)xs + g * 2048 + ((row ^ g) << 4)) = (u32x4){w[0], w[1], w[2], w[3]};
        }
    }

    int wave = t >> 6, lane = t & 63;
    int i16 = lane & 15, q4 = lane >> 4;

    f32x4 acc[8][4];

    __syncthreads();   // xs ready

    // ---- layer 0: h0 = relu([x_q|x_p] @ W0^T + b0), K=64 padded ----
    {
        #pragma unroll
        for (int mt = 0; mt < 8; ++mt)
            #pragma unroll
            for (int j = 0; j < 4; ++j)
                acc[mt][j] = (f32x4){0.f, 0.f, 0.f, 0.f};
        const unsigned short* Bb0 = W0p + wave * 4096 + lane * 8;
        const char* xb = (const char*)xs;
        #pragma unroll
        for (int s = 0; s < 2; ++s) {
            bf16x8 bfr[4];
            #pragma unroll
            for (int j = 0; j < 4; ++j)
                bfr[j] = *(const bf16x8*)(Bb0 + s * 2048 + j * 512);
            int g = s * 4 + q4;
            const char* A0 = xb + g * 2048 + ((i16 ^ (g & 7)) << 4);
            #pragma unroll
            for (int mt = 0; mt < 8; ++mt) {
                bf16x8 a = *(const bf16x8*)(A0 + mt * 256);
                #pragma unroll
                for (int j = 0; j < 4; ++j)
                    MFMA_A(acc[mt][j], a, bfr[j]);
                __builtin_amdgcn_sched_barrier(0);   // cap A-load batching
            }
        }
        store_h(acc, b0, hsm, wave, i16, q4, lane);   // each wave writes its own cols
    }

    // ---- layers 1..3: mt-outer rolling-A + B X/Y ping-pong ----
    // A byte addr for step s: [parity base] + s*8192 + mt*256.
    int A_evenoff = (q4 << 11) + ((i16 ^ q4) << 4);
    const char* hbe = (const char*)hsm + A_evenoff;          // even-step A base
    const char* hbo = (const char*)hsm + (A_evenoff ^ 64);   // odd-step A base

    #pragma unroll 1
    for (int l = 0; l < 3; ++l) {
        const float* bl = (l == 0) ? b1 : (l == 1) ? b2 : b3;
        // B fragments: one shared per-lane address; j at +1024B, s at +4096B.
        const unsigned short* Bb = Wp + (size_t)l * 262144 + wave * 32768 + lane * 8;

        // prefetch B(0) -> X, B(1) -> Y; these ride the barrier drain
        bf16x8 X0 = *(const bf16x8*)(Bb);
        bf16x8 X1 = *(const bf16x8*)(Bb + 512);
        bf16x8 X2 = *(const bf16x8*)(Bb + 1024);
        bf16x8 X3 = *(const bf16x8*)(Bb + 1536);
        bf16x8 Y0 = *(const bf16x8*)(Bb + 2048);
        bf16x8 Y1 = *(const bf16x8*)(Bb + 2560);
        bf16x8 Y2 = *(const bf16x8*)(Bb + 3072);
        bf16x8 Y3 = *(const bf16x8*)(Bb + 3584);

        __syncthreads();   // h ready

        #pragma unroll
        for (int mt = 0; mt < 8; ++mt)
            #pragma unroll
            for (int j = 0; j < 4; ++j)
                acc[mt][j] = (f32x4){0.f, 0.f, 0.f, 0.f};

        // A(0)
        bf16x8 A0 = *(const bf16x8*)(hbe);
        bf16x8 A1 = *(const bf16x8*)(hbe + 256);
        bf16x8 A2 = *(const bf16x8*)(hbe + 512);
        bf16x8 A3 = *(const bf16x8*)(hbe + 768);
        bf16x8 A4 = *(const bf16x8*)(hbe + 1024);
        bf16x8 A5 = *(const bf16x8*)(hbe + 1280);
        bf16x8 A6 = *(const bf16x8*)(hbe + 1536);
        bf16x8 A7 = *(const bf16x8*)(hbe + 1792);

        #pragma unroll 1
        for (int s = 0; s < 16; s += 2) {
            int s2 = (s + 2 < 16) ? s + 2 : 14;            // clamped (tail dummies)
            int s3 = (s + 3 < 16) ? s + 3 : 15;
            const char* pnO = hbo + ((s + 1) << 13);       // A(s+1), odd
            const char* pnE = hbe + (s2 << 13);            // A(s+2), even
            const unsigned short* BX = Bb + s2 * 2048;     // B(s+2) -> X
            const unsigned short* BY = Bb + s3 * 2048;     // B(s+3) -> Y

            // ===== even step s: consume A,X; reload A[mt] <- A(s+1) after use =====
            CLUSTER(A0, X0, X1, X2, X3, 0)  A0 = *(const bf16x8*)(pnO);
            CLUSTER(A1, X0, X1, X2, X3, 1)  A1 = *(const bf16x8*)(pnO + 256);
            CLUSTER(A2, X0, X1, X2, X3, 2)  A2 = *(const bf16x8*)(pnO + 512);
            CLUSTER(A3, X0, X1, X2, X3, 3)  A3 = *(const bf16x8*)(pnO + 768);
            CLUSTER(A4, X0, X1, X2, X3, 4)  A4 = *(const bf16x8*)(pnO + 1024);
            CLUSTER(A5, X0, X1, X2, X3, 5)  A5 = *(const bf16x8*)(pnO + 1280);
            CLUSTER(A6, X0, X1, X2, X3, 6)  A6 = *(const bf16x8*)(pnO + 1536);
            CLUSTER(A7, X0, X1, X2, X3, 7)  A7 = *(const bf16x8*)(pnO + 1792);

            // ===== odd step s+1: X dead -> reload X <- B(s+2) up front =====
            X0 = *(const bf16x8*)(BX);
            X1 = *(const bf16x8*)(BX + 512);
            X2 = *(const bf16x8*)(BX + 1024);
            X3 = *(const bf16x8*)(BX + 1536);
            // consume A,Y; reload A[mt] <- A(s+2) after use
            CLUSTER(A0, Y0, Y1, Y2, Y3, 0)  A0 = *(const bf16x8*)(pnE);
            CLUSTER(A1, Y0, Y1, Y2, Y3, 1)  A1 = *(const bf16x8*)(pnE + 256);
            CLUSTER(A2, Y0, Y1, Y2, Y3, 2)  A2 = *(const bf16x8*)(pnE + 512);
            CLUSTER(A3, Y0, Y1, Y2, Y3, 3)  A3 = *(const bf16x8*)(pnE + 768);
            CLUSTER(A4, Y0, Y1, Y2, Y3, 4)  A4 = *(const bf16x8*)(pnE + 1024);
            CLUSTER(A5, Y0, Y1, Y2, Y3, 5)  A5 = *(const bf16x8*)(pnE + 1280);
            CLUSTER(A6, Y0, Y1, Y2, Y3, 6)  A6 = *(const bf16x8*)(pnE + 1536);
            CLUSTER(A7, Y0, Y1, Y2, Y3, 7)  A7 = *(const bf16x8*)(pnE + 1792);
            // Y dead -> reload Y <- B(s+3)
            Y0 = *(const bf16x8*)(BY);
            Y1 = *(const bf16x8*)(BY + 512);
            Y2 = *(const bf16x8*)(BY + 1024);
            Y3 = *(const bf16x8*)(BY + 1536);
        }
        __syncthreads();   // all reads of h done before overwrite

        if (l < 2) {
            store_h(acc, bl, hsm, wave, i16, q4, lane);
        } else {
            // layer 3: bias + relu + sum over all 128 rows -> per-block partial
            #pragma unroll
            for (int j = 0; j < 4; ++j) {
                int col = (wave * 4 + j) * 16 + i16;
                float bb = bl[col];
                float sum = 0.f;
                #pragma unroll
                for (int mt = 0; mt < 8; ++mt) {
                    #pragma unroll
                    for (int r = 0; r < 4; ++r)
                        sum += fmaxf(acc[mt][j][r] + bb, 0.f);
                    __builtin_amdgcn_sched_barrier(0);   // cap acc-read batching
                }
                sum += __shfl_xor(sum, 16);
                sum += __shfl_xor(sum, 32);
                if (q4 == 0) P[(size_t)blk * 512 + col] = sum;
            }
        }
    }
}

// ---------------- tail: reduce P + layers 4,5,6 + log_softmax ----
__global__ __launch_bounds__(1024) void k_tail(
    const float* __restrict__ P, const float* __restrict__ qst,
    const float* __restrict__ W4v, const float* __restrict__ b4,
    const float* __restrict__ W5v, const float* __restrict__ b5,
    const float* __restrict__ W6, const float* __restrict__ b6,
    float* __restrict__ out)
{
    int b = blockIdx.x, t = threadIdx.x;
    __shared__ __align__(16) float z[768];
    __shared__ __align__(16) float ps[1024];
    __shared__ __align__(16) float h4[512];
    __shared__ float h5[512];
    __shared__ float logits[28];
    __shared__ float red[2];

    if (t < 512) {     // reduce the 32 per-(b,p-pair)-block partials
        float s = 0.f;
        const float* Pb = P + (size_t)b * 32 * 512 + t;
        #pragma unroll 8
        for (int c = 0; c < 32; ++c) s += Pb[c * 512];
        z[t] = s;
    } else if (t < 768) {
        z[t] = qst[b * 256 + (t - 512)];
    }
    __syncthreads();
    {   // layer 4: 768 -> 512, 2-way k-split per output
        int o = t & 511, hf = t >> 9;
        float acc = 0.f;
        const float4* Wv = (const float4*)W4v;
        const float4* z4 = (const float4*)z;
        #pragma unroll 4
        for (int kb = hf * 96; kb < hf * 96 + 96; ++kb) {
            float4 w = Wv[kb * 512 + o];
            float4 zz = z4[kb];
            acc = fmaf(w.x, zz.x, acc);
            acc = fmaf(w.y, zz.y, acc);
            acc = fmaf(w.z, zz.z, acc);
            acc = fmaf(w.w, zz.w, acc);
        }
        ps[t] = acc;
    }
    __syncthreads();
    if (t < 512) h4[t] = fmaxf(ps[t] + ps[t + 512] + b4[t], 0.f);
    __syncthreads();
    {   // layer 5: 512 -> 512, 2-way k-split per output
        int o = t & 511, hf = t >> 9;
        float acc = 0.f;
        const float4* Wv = (const float4*)W5v;
        const float4* h44 = (const float4*)h4;
        #pragma unroll 4
        for (int kb = hf * 64; kb < hf * 64 + 64; ++kb) {
            float4 w = Wv[kb * 512 + o];
            float4 hh = h44[kb];
            acc = fmaf(w.x, hh.x, acc);
            acc = fmaf(w.y, hh.y, acc);
            acc = fmaf(w.z, hh.z, acc);
            acc = fmaf(w.w, hh.w, acc);
        }
        ps[t] = acc;
    }
    __syncthreads();
    if (t < 512) h5[t] = fmaxf(ps[t] + ps[t + 512] + b5[t], 0.f);
    __syncthreads();
    {   // layer 6: 512 -> 28 (32 lanes per output)
        int o = t >> 5, c = t & 31;
        if (o < 28) {
            float acc = 0.f;
            for (int k = c; k < 512; k += 32) acc = fmaf(W6[o * 512 + k], h5[k], acc);
            acc += __shfl_xor(acc, 1);
            acc += __shfl_xor(acc, 2);
            acc += __shfl_xor(acc, 4);
            acc += __shfl_xor(acc, 8);
            acc += __shfl_xor(acc, 16);
            if (c == 0) logits[o] = acc + b6[o];
        }
    }
    __syncthreads();
    if (t == 0) {
        float mx = -1e30f;
        for (int cc = 0; cc < 28; ++cc) mx = fmaxf(mx, logits[cc]);
        float se = 0.f;
        for (int cc = 0; cc < 28; ++cc) se += expf(logits[cc] - mx);
        red[0] = mx; red[1] = logf(se);
    }
    __syncthreads();
    if (t < 28) out[b * 28 + t] = logits[t] - red[0] - red[1];
}

extern "C" void kernel_launch(void* const* d_in, const int* in_sizes, int n_in,
                              void* d_out, int out_size, void* d_ws, size_t ws_size,
                              hipStream_t stream)
{
    const float* x   = (const float*)d_in[0];
    const float* qst = (const float*)d_in[1];
    const float* W0  = (const float*)d_in[2];
    const float* b0  = (const float*)d_in[3];
    const float* W1  = (const float*)d_in[4];
    const float* b1  = (const float*)d_in[5];
    const float* W2  = (const float*)d_in[6];
    const float* b2  = (const float*)d_in[7];
    const float* W3  = (const float*)d_in[8];
    const float* b3  = (const float*)d_in[9];
    const float* W4  = (const float*)d_in[10];
    const float* b4  = (const float*)d_in[11];
    const float* W5  = (const float*)d_in[12];
    const float* b5  = (const float*)d_in[13];
    const float* W6  = (const float*)d_in[14];
    const float* b6  = (const float*)d_in[15];
    float* out = (float*)d_out;

    char* ws = (char*)d_ws;
    unsigned short* Wp  = (unsigned short*)(ws);             // 1.5 MiB
    unsigned short* W0p = (unsigned short*)(ws + 1572864);   // 64 KiB
    float*          W4v = (float*)(ws + 1638400);            // 1.5 MiB
    float*          W5v = (float*)(ws + 3211264);            // 1 MiB
    float*          P   = (float*)(ws + 4259840);            // 2 MiB partials

    k_prep <<<NPV_TOTAL / 256, 256, 0, stream>>>(W1, W2, W3, W0, W4, W5,
                                                 Wp, W0p, W4v, W5v);
    k_fused<<<1024, 512, 0, stream>>>(x, Wp, W0p, b0, b1, b2, b3, P);
    k_tail <<<32, 1024, 0, stream>>>(P, qst, W4v, b4, W5v, b5, W6, b6, out);
}

// Round 13
// 322.949 us; speedup vs baseline: 3.3307x; 3.3307x over previous
//
#include <hip/hip_runtime.h>
#include <math.h>

// Relational Network fused pipeline for MI355X (gfx950).
// B=32, D=64, K=26, QST=256, G=[512x6, 28], AGG at layer 4.
//
// Round 18: REVERT to round 10 (best measured: 324.9us total, k_fused 232us,
// VGPR 104, zero spill, absmax 8.0) + vectorized k_prep only.
//  - M=128 line closed after R12-R17: the allocator will not home a
//    128-value accumulator in AGPRs (builtin = VGPR-form MFMA; empty-asm
//    "+a" pin adds copies; asm-tied "+a" MFMA shuttles quads around every
//    fence -> 3.4GB spill). M=64 with acc[4][4]=64 values fits the
//    128-arch budget at 2 waves/EU with the X/Y + even/odd pipeline.
//  - k_prep vectorized: 8 bf16 (or 4 f32) per thread, single 16B stores
//    into identical layouts (s=kq>>2, q4=kq&3, j contiguous) -> ~5x fewer
//    store instructions, coalesced reads. Same bits as scalar version.

typedef __attribute__((ext_vector_type(8))) short bf16x8;   // 8 bf16 in 4 VGPRs
typedef __attribute__((ext_vector_type(4))) float f32x4;    // MFMA 16x16 accumulator
typedef __attribute__((ext_vector_type(4))) unsigned int u32x4;

__device__ __forceinline__ unsigned short f2bf(float f) {
    union { float f; unsigned u; } x; x.f = f;
    unsigned r = x.u + 0x7fffu + ((x.u >> 16) & 1u);   // RNE
    return (unsigned short)(r >> 16);
}

// ---------------- pack / transpose weights (vectorized) ----------------
// Wp layout per layer: [wave(8)][s(16)][jj(4)][lane(64)][j(8)] bf16,
//   value = W[n][k], n = (wave*4+jj)*16 + (lane&15), k = s*32 + (lane>>4)*8 + j.
// W0p: same with s(2) over padded K=64 (k >= 52 -> 0).
// W4v/W5v: fp32 [k/4][512 out][4] so k_tail threads stream float4.
#define NPV_WP   98304            // 3 * 512 * 64   (8 bf16/thread)
#define NPV_W0P  4096             // 512 * 8        (8 bf16/thread)
#define NPV_W4   98304            // 768*512/4      (4 f32/thread)
#define NPV_W5   65536            // 512*512/4
#define NPV_TOTAL (NPV_WP + NPV_W0P + NPV_W4 + NPV_W5)   // 266240 = 1040*256
__global__ void k_prep(const float* __restrict__ W1, const float* __restrict__ W2,
                       const float* __restrict__ W3, const float* __restrict__ W0,
                       const float* __restrict__ W4, const float* __restrict__ W5,
                       unsigned short* __restrict__ Wp,   // [3][262144] bf16
                       unsigned short* __restrict__ W0p,  // [32768] bf16
                       float* __restrict__ W4v,           // [192][512][4] fp32
                       float* __restrict__ W5v)           // [128][512][4] fp32
{
    int f = blockIdx.x * 256 + threadIdx.x;
    if (f < NPV_WP) {
        int l = f >> 15, r = f & 32767;
        int n = r >> 6, kq = r & 63;                 // k0 = kq*8
        const float* W = (l == 0) ? W1 : (l == 1) ? W2 : W3;
        const float* src = W + n * 512 + kq * 8;
        int s = kq >> 2, q4 = kq & 3;
        int wv = n >> 6, jj = (n >> 4) & 3, i16 = n & 15;
        int lane = q4 * 16 + i16;
        unsigned w[4];
        #pragma unroll
        for (int h = 0; h < 4; ++h)
            w[h] = (unsigned)f2bf(src[h * 2]) | ((unsigned)f2bf(src[h * 2 + 1]) << 16);
        *(u32x4*)(Wp + (size_t)l * 262144 + ((((wv * 16 + s) * 4 + jj) * 64 + lane) << 3))
            = (u32x4){w[0], w[1], w[2], w[3]};
    } else if (f < NPV_WP + NPV_W0P) {
        int g = f - NPV_WP;
        int n = g >> 3, kq = g & 7;
        int s = kq >> 2, q4 = kq & 3;
        int wv = n >> 6, jj = (n >> 4) & 3, i16 = n & 15;
        int lane = q4 * 16 + i16;
        unsigned w[4];
        #pragma unroll
        for (int h = 0; h < 4; ++h) {
            int k0 = kq * 8 + h * 2, k1 = k0 + 1;
            float f0 = (k0 < 52) ? W0[n * 52 + k0] : 0.f;
            float f1 = (k1 < 52) ? W0[n * 52 + k1] : 0.f;
            w[h] = (unsigned)f2bf(f0) | ((unsigned)f2bf(f1) << 16);
        }
        *(u32x4*)(W0p + ((((wv * 2 + s) * 4 + jj) * 64 + lane) << 3))
            = (u32x4){w[0], w[1], w[2], w[3]};
    } else if (f < NPV_WP + NPV_W0P + NPV_W4) {
        int g = f - (NPV_WP + NPV_W0P);
        int o = g / 192, kb = g % 192;
        float4 w = *(const float4*)(W4 + (size_t)o * 768 + kb * 4);
        *(float4*)(W4v + (size_t)kb * 2048 + o * 4) = w;
    } else {
        int g = f - (NPV_WP + NPV_W0P + NPV_W4);
        int o = g >> 7, kb = g & 127;
        float4 w = *(const float4*)(W5 + (size_t)o * 512 + kb * 4);
        *(float4*)(W5v + (size_t)kb * 2048 + o * 4) = w;
    }
}

// ---------------- h-store epilogue: bias + relu + bf16 LDS write ----
// Granule-column-major target: byte = (col>>3)*1024 + (row ^ ((col>>3)&7))*16
//                                    + (col&7)*2.
// DPP quad_perm swap on f32, then v_cvt_pk_bf16_f32 packs (col, col+1) into
// one dword; even lanes write ds_write_b32.
__device__ __forceinline__ void store_h(const f32x4 (&acc)[4][4], const float* __restrict__ bl,
                                        unsigned short* hsm, int wave, int i16, int q4, int lane)
{
    char* base = (char*)hsm;
    #pragma unroll
    for (int j = 0; j < 4; ++j) {
        int col = (wave * 4 + j) * 16 + i16;
        int g = col >> 3;
        int e = g & 7;
        float bb = bl[col];
        char* colbase = base + g * 1024 + ((col & 7) << 1);
        #pragma unroll
        for (int mt = 0; mt < 4; ++mt) {
            #pragma unroll
            for (int r = 0; r < 4; ++r) {
                int row = mt * 16 + q4 * 4 + r;
                float v = fmaxf(acc[mt][j][r] + bb, 0.f);
                int vi = __float_as_int(v);
                // quad_perm [1,0,3,2]: each lane gets partner (lane^1)'s f32
                int swi = __builtin_amdgcn_update_dpp(0, vi, 0xB1, 0xF, 0xF, true);
                if ((lane & 1) == 0) {
                    unsigned pk;
                    asm("v_cvt_pk_bf16_f32 %0, %1, %2" : "=v"(pk) : "v"(vi), "v"(swi));
                    int slot = row ^ e;
                    *(unsigned*)(colbase + slot * 16) = pk;
                }
            }
        }
    }
}

#define CLUSTER(AV0, AV1, AV2, AV3, BV, JJ)                                              \
    __builtin_amdgcn_s_setprio(1);                                                      \
    acc[0][JJ] = __builtin_amdgcn_mfma_f32_16x16x32_bf16(AV0, BV, acc[0][JJ], 0, 0, 0); \
    acc[1][JJ] = __builtin_amdgcn_mfma_f32_16x16x32_bf16(AV1, BV, acc[1][JJ], 0, 0, 0); \
    acc[2][JJ] = __builtin_amdgcn_mfma_f32_16x16x32_bf16(AV2, BV, acc[2][JJ], 0, 0, 0); \
    acc[3][JJ] = __builtin_amdgcn_mfma_f32_16x16x32_bf16(AV3, BV, acc[3][JJ], 0, 0, 0); \
    __builtin_amdgcn_s_setprio(0);                                                      \
    __builtin_amdgcn_sched_barrier(0);

// ---------------- fused layers 0..3 ----------------
// One block per (b,p): 64 pair-rows. h tile 64x512 bf16 in LDS,
// granule-column-major: hsm[g=k>>3][slot=row^(g&7)][8 shorts].
// 8 waves; wave w computes cols [w*64, w*64+64): acc = 4 (row tiles) x 4 (col tiles).
__global__ __launch_bounds__(512, 2) void k_fused(
    const float* __restrict__ x,
    const unsigned short* __restrict__ Wp,
    const unsigned short* __restrict__ W0p,
    const float* __restrict__ b0, const float* __restrict__ b1,
    const float* __restrict__ b2, const float* __restrict__ b3,
    float* __restrict__ P)
{
    __shared__ __align__(16) unsigned short hsm[64 * 512];   // 64 KiB
    __shared__ __align__(16) unsigned short xs[8 * 64 * 8];  // 8 KiB (x-pair tile)
    int t = threadIdx.x;
    int blk = blockIdx.x;
    int b = blk >> 6, p = blk & 63;

    // ---- stage xs: [g(8)][slot=row^g][8] bf16 of [x[b,row,:26] | x[b,p,:26] | 0] ----
    {
        int row = t >> 3, gr = t & 7;
        const float* xq = x + (size_t)(b * 64 + row) * 26;
        const float* xp = x + (size_t)(b * 64 + p) * 26;
        unsigned w[4];
        #pragma unroll
        for (int h = 0; h < 4; ++h) {
            int k0 = gr * 8 + h * 2;
            int k1 = k0 + 1;
            float f0 = (k0 < 26) ? xq[k0] : (k0 < 52 ? xp[k0 - 26] : 0.f);
            float f1 = (k1 < 26) ? xq[k1] : (k1 < 52 ? xp[k1 - 26] : 0.f);
            w[h] = (unsigned)f2bf(f0) | ((unsigned)f2bf(f1) << 16);
        }
        *(u32x4*)((char*)xs + gr * 1024 + ((row ^ gr) << 4)) = (u32x4){w[0], w[1], w[2], w[3]};
    }

    int wave = t >> 6, lane = t & 63;
    int i16 = lane & 15, q4 = lane >> 4;

    f32x4 acc[4][4];

    __syncthreads();   // xs ready

    // ---- layer 0: h0 = relu([x_q|x_p] @ W0^T + b0), K=64 padded ----
    {
        #pragma unroll
        for (int mt = 0; mt < 4; ++mt)
            #pragma unroll
            for (int j = 0; j < 4; ++j)
                acc[mt][j] = (f32x4){0.f, 0.f, 0.f, 0.f};
        const unsigned short* Bb0 = W0p + wave * 4096 + lane * 8;
        const char* xb = (const char*)xs;
        #pragma unroll
        for (int s = 0; s < 2; ++s) {
            bf16x8 bfr[4];
            #pragma unroll
            for (int j = 0; j < 4; ++j)
                bfr[j] = *(const bf16x8*)(Bb0 + s * 2048 + j * 512);
            int g = s * 4 + q4;
            const char* A0 = xb + g * 1024 + ((i16 ^ g) << 4);
            #pragma unroll
            for (int mt = 0; mt < 4; ++mt) {
                bf16x8 a = *(const bf16x8*)(A0 + mt * 256);
                #pragma unroll
                for (int j = 0; j < 4; ++j)
                    acc[mt][j] = __builtin_amdgcn_mfma_f32_16x16x32_bf16(a, bfr[j], acc[mt][j], 0, 0, 0);
            }
        }
        store_h(acc, b0, hsm, wave, i16, q4, lane);   // each wave writes its own cols
    }

    // ---- layers 1..3: X/Y B-dbuf (2-step-ahead), A even/odd dbuf (1 ahead) ----
    // A byte addr for step s: hsm + s*4096 + A_base(s&1) + mt*256.
    int A_even = (q4 << 10) + ((i16 ^ q4) << 4);
    const char* hbe = (const char*)hsm + A_even;              // even-step A base
    const char* hbo = (const char*)hsm + 4096 + (A_even ^ 64); // odd-step A base

    #pragma unroll 1
    for (int l = 0; l < 3; ++l) {
        const float* bl = (l == 0) ? b1 : (l == 1) ? b2 : b3;
        // B fragments: one shared per-lane address; j at +1024B, s at +4096B.
        const unsigned short* Bb = Wp + (size_t)l * 262144 + wave * 32768 + lane * 8;

        // prefetch B(0) -> X, B(1) -> Y; these ride the barrier drain
        bf16x8 X0 = *(const bf16x8*)(Bb);
        bf16x8 X1 = *(const bf16x8*)(Bb + 512);
        bf16x8 X2 = *(const bf16x8*)(Bb + 1024);
        bf16x8 X3 = *(const bf16x8*)(Bb + 1536);
        bf16x8 Y0 = *(const bf16x8*)(Bb + 2048);
        bf16x8 Y1 = *(const bf16x8*)(Bb + 2560);
        bf16x8 Y2 = *(const bf16x8*)(Bb + 3072);
        bf16x8 Y3 = *(const bf16x8*)(Bb + 3584);

        __syncthreads();   // h ready

        #pragma unroll
        for (int mt = 0; mt < 4; ++mt)
            #pragma unroll
            for (int j = 0; j < 4; ++j)
                acc[mt][j] = (f32x4){0.f, 0.f, 0.f, 0.f};

        // A(0)
        bf16x8 aE0 = *(const bf16x8*)(hbe);
        bf16x8 aE1 = *(const bf16x8*)(hbe + 256);
        bf16x8 aE2 = *(const bf16x8*)(hbe + 512);
        bf16x8 aE3 = *(const bf16x8*)(hbe + 768);
        bf16x8 aO0, aO1, aO2, aO3;

        #pragma unroll 1
        for (int s = 0; s < 16; s += 2) {
            // ===== even step s: consume aE*, X*; reload X = B(s+2), aO = A(s+1) =====
            {
                const unsigned short* BX = Bb + ((s + 2 < 16) ? (s + 2) : 14) * 2048;
                const char* po = hbo + (s << 12);      // A(s+1)
                CLUSTER(aE0, aE1, aE2, aE3, X0, 0)
                X0 = *(const bf16x8*)(BX);
                aO0 = *(const bf16x8*)(po);
                aO1 = *(const bf16x8*)(po + 256);
                CLUSTER(aE0, aE1, aE2, aE3, X1, 1)
                X1 = *(const bf16x8*)(BX + 512);
                aO2 = *(const bf16x8*)(po + 512);
                aO3 = *(const bf16x8*)(po + 768);
                CLUSTER(aE0, aE1, aE2, aE3, X2, 2)
                X2 = *(const bf16x8*)(BX + 1024);
                CLUSTER(aE0, aE1, aE2, aE3, X3, 3)
                X3 = *(const bf16x8*)(BX + 1536);
            }
            // ===== odd step s+1: consume aO*, Y*; reload Y = B(s+3), aE = A(s+2) =====
            {
                const unsigned short* BY = Bb + ((s + 3 < 16) ? (s + 3) : 15) * 2048;
                const char* pe = hbe + ((s + 2 < 16 ? s + 2 : 14) << 12);   // A(s+2)
                CLUSTER(aO0, aO1, aO2, aO3, Y0, 0)
                Y0 = *(const bf16x8*)(BY);
                aE0 = *(const bf16x8*)(pe);
                aE1 = *(const bf16x8*)(pe + 256);
                CLUSTER(aO0, aO1, aO2, aO3, Y1, 1)
                Y1 = *(const bf16x8*)(BY + 512);
                aE2 = *(const bf16x8*)(pe + 512);
                aE3 = *(const bf16x8*)(pe + 768);
                CLUSTER(aO0, aO1, aO2, aO3, Y2, 2)
                Y2 = *(const bf16x8*)(BY + 1024);
                CLUSTER(aO0, aO1, aO2, aO3, Y3, 3)
                Y3 = *(const bf16x8*)(BY + 1536);
            }
        }
        __syncthreads();   // all reads of h done before overwrite

        if (l < 2) {
            store_h(acc, bl, hsm, wave, i16, q4, lane);
        } else {
            // layer 3: bias + relu + sum over 64 rows -> per-block partial P[blk][col]
            #pragma unroll
            for (int j = 0; j < 4; ++j) {
                int col = (wave * 4 + j) * 16 + i16;
                float bb = bl[col];
                float sum = 0.f;
                #pragma unroll
                for (int mt = 0; mt < 4; ++mt)
                    #pragma unroll
                    for (int r = 0; r < 4; ++r)
                        sum += fmaxf(acc[mt][j][r] + bb, 0.f);
                sum += __shfl_xor(sum, 16);
                sum += __shfl_xor(sum, 32);
                if (q4 == 0) P[(size_t)blk * 512 + col] = sum;
            }
        }
    }
}

// ---------------- tail: reduce P + layers 4,5,6 + log_softmax ----
__global__ __launch_bounds__(1024) void k_tail(
    const float* __restrict__ P, const float* __restrict__ qst,
    const float* __restrict__ W4v, const float* __restrict__ b4,
    const float* __restrict__ W5v, const float* __restrict__ b5,
    const float* __restrict__ W6, const float* __restrict__ b6,
    float* __restrict__ out)
{
    int b = blockIdx.x, t = threadIdx.x;
    __shared__ __align__(16) float z[768];
    __shared__ __align__(16) float ps[1024];
    __shared__ __align__(16) float h4[512];
    __shared__ float h5[512];
    __shared__ float logits[28];
    __shared__ float red[2];

    if (t < 512) {     // reduce the 64 per-(b,p)-block partials
        float s = 0.f;
        const float* Pb = P + (size_t)b * 64 * 512 + t;
        #pragma unroll 8
        for (int c = 0; c < 64; ++c) s += Pb[c * 512];
        z[t] = s;
    } else if (t < 768) {
        z[t] = qst[b * 256 + (t - 512)];
    }
    __syncthreads();
    {   // layer 4: 768 -> 512, 2-way k-split per output
        int o = t & 511, hf = t >> 9;
        float acc = 0.f;
        const float4* Wv = (const float4*)W4v;
        const float4* z4 = (const float4*)z;
        #pragma unroll 4
        for (int kb = hf * 96; kb < hf * 96 + 96; ++kb) {
            float4 w = Wv[kb * 512 + o];
            float4 zz = z4[kb];
            acc = fmaf(w.x, zz.x, acc);
            acc = fmaf(w.y, zz.y, acc);
            acc = fmaf(w.z, zz.z, acc);
            acc = fmaf(w.w, zz.w, acc);
        }
        ps[t] = acc;
    }
    __syncthreads();
    if (t < 512) h4[t] = fmaxf(ps[t] + ps[t + 512] + b4[t], 0.f);
    __syncthreads();
    {   // layer 5: 512 -> 512, 2-way k-split per output
        int o = t & 511, hf = t >> 9;
        float acc = 0.f;
        const float4* Wv = (const float4*)W5v;
        const float4* h44 = (const float4*)h4;
        #pragma unroll 4
        for (int kb = hf * 64; kb < hf * 64 + 64; ++kb) {
            float4 w = Wv[kb * 512 + o];
            float4 hh = h44[kb];
            acc = fmaf(w.x, hh.x, acc);
            acc = fmaf(w.y, hh.y, acc);
            acc = fmaf(w.z, hh.z, acc);
            acc = fmaf(w.w, hh.w, acc);
        }
        ps[t] = acc;
    }
    __syncthreads();
    if (t < 512) h5[t] = fmaxf(ps[t] + ps[t + 512] + b5[t], 0.f);
    __syncthreads();
    {   // layer 6: 512 -> 28 (32 lanes per output)
        int o = t >> 5, c = t & 31;
        if (o < 28) {
            float acc = 0.f;
            for (int k = c; k < 512; k += 32) acc = fmaf(W6[o * 512 + k], h5[k], acc);
            acc += __shfl_xor(acc, 1);
            acc += __shfl_xor(acc, 2);
            acc += __shfl_xor(acc, 4);
            acc += __shfl_xor(acc, 8);
            acc += __shfl_xor(acc, 16);
            if (c == 0) logits[o] = acc + b6[o];
        }
    }
    __syncthreads();
    if (t == 0) {
        float mx = -1e30f;
        for (int cc = 0; cc < 28; ++cc) mx = fmaxf(mx, logits[cc]);
        float se = 0.f;
        for (int cc = 0; cc < 28; ++cc) se += expf(logits[cc] - mx);
        red[0] = mx; red[1] = logf(se);
    }
    __syncthreads();
    if (t < 28) out[b * 28 + t] = logits[t] - red[0] - red[1];
}

extern "C" void kernel_launch(void* const* d_in, const int* in_sizes, int n_in,
                              void* d_out, int out_size, void* d_ws, size_t ws_size,
                              hipStream_t stream)
{
    const float* x   = (const float*)d_in[0];
    const float* qst = (const float*)d_in[1];
    const float* W0  = (const float*)d_in[2];
    const float* b0  = (const float*)d_in[3];
    const float* W1  = (const float*)d_in[4];
    const float* b1  = (const float*)d_in[5];
    const float* W2  = (const float*)d_in[6];
    const float* b2  = (const float*)d_in[7];
    const float* W3  = (const float*)d_in[8];
    const float* b3  = (const float*)d_in[9];
    const float* W4  = (const float*)d_in[10];
    const float* b4  = (const float*)d_in[11];
    const float* W5  = (const float*)d_in[12];
    const float* b5  = (const float*)d_in[13];
    const float* W6  = (const float*)d_in[14];
    const float* b6  = (const float*)d_in[15];
    float* out = (float*)d_out;

    char* ws = (char*)d_ws;
    unsigned short* Wp  = (unsigned short*)(ws);             // 1.5 MiB
    unsigned short* W0p = (unsigned short*)(ws + 1572864);   // 64 KiB
    float*          W4v = (float*)(ws + 1638400);            // 1.5 MiB
    float*          W5v = (float*)(ws + 3211264);            // 1 MiB
    float*          P   = (float*)(ws + 4259840);            // 4 MiB partials

    k_prep <<<NPV_TOTAL / 256, 256, 0, stream>>>(W1, W2, W3, W0, W4, W5,
                                                 Wp, W0p, W4v, W5v);
    k_fused<<<2048, 512, 0, stream>>>(x, Wp, W0p, b0, b1, b2, b3, P);
    k_tail <<<32, 1024, 0, stream>>>(P, qst, W4v, b4, W5v, b5, W6, b6, out);
}

// Round 14
// 322.118 us; speedup vs baseline: 3.3393x; 1.0026x over previous
//
#include <hip/hip_runtime.h>
#include <math.h>

// Relational Network fused pipeline for MI355X (gfx950).
// B=32, D=64, K=26, QST=256, G=[512x6, 28], AGG at layer 4.
//
// Round 19 changes vs round 18 (round 18 = best: 322.9us, k_fused 246us):
//  - hsm DOUBLE-BUFFER (2 x 64KB + 8KB xs = 136KB <= 160KB LDS): layer l
//    reads buf[l&1], store_h writes buf[(l+1)&1]. Removes the
//    "all-reads-done-before-overwrite" barrier -> 4 barriers/block instead
//    of 7, and each wave starts store_h right after ITS OWN k-loop instead
//    of waiting for all waves (wave-skew absorbed).
//  - Next-layer B(0)/B(1) prefetch issued BEFORE store_h: its ~300cyc L2
//    latency hides under store_h's ~800cyc VALU work, so the barrier's
//    implicit vmcnt(0) drain finds the loads already done (previously every
//    layer boundary stalled all waves on the full L2 latency).
//  - Rationale: per-SIMD per-step arithmetic shows MFMA(620cyc) and the B
//    L2-stream(546cyc) are running SERIALLY (observed ~1200cyc/step); the
//    barrier drains + epilogue serialization are the main schedule overhead
//    at the register-feasible occupancy (2 waves/SIMD; 4-waves+pipeline is
//    infeasible: needs >=76 arch regs vs 64 available at that occupancy).
//  - k_prep (vectorized) and k_tail unchanged from round 18.

typedef __attribute__((ext_vector_type(8))) short bf16x8;   // 8 bf16 in 4 VGPRs
typedef __attribute__((ext_vector_type(4))) float f32x4;    // MFMA 16x16 accumulator
typedef __attribute__((ext_vector_type(4))) unsigned int u32x4;

__device__ __forceinline__ unsigned short f2bf(float f) {
    union { float f; unsigned u; } x; x.f = f;
    unsigned r = x.u + 0x7fffu + ((x.u >> 16) & 1u);   // RNE
    return (unsigned short)(r >> 16);
}

// ---------------- pack / transpose weights (vectorized) ----------------
// Wp layout per layer: [wave(8)][s(16)][jj(4)][lane(64)][j(8)] bf16,
//   value = W[n][k], n = (wave*4+jj)*16 + (lane&15), k = s*32 + (lane>>4)*8 + j.
// W0p: same with s(2) over padded K=64 (k >= 52 -> 0).
// W4v/W5v: fp32 [k/4][512 out][4] so k_tail threads stream float4.
#define NPV_WP   98304            // 3 * 512 * 64   (8 bf16/thread)
#define NPV_W0P  4096             // 512 * 8        (8 bf16/thread)
#define NPV_W4   98304            // 768*512/4      (4 f32/thread)
#define NPV_W5   65536            // 512*512/4
#define NPV_TOTAL (NPV_WP + NPV_W0P + NPV_W4 + NPV_W5)   // 266240 = 1040*256
__global__ void k_prep(const float* __restrict__ W1, const float* __restrict__ W2,
                       const float* __restrict__ W3, const float* __restrict__ W0,
                       const float* __restrict__ W4, const float* __restrict__ W5,
                       unsigned short* __restrict__ Wp,   // [3][262144] bf16
                       unsigned short* __restrict__ W0p,  // [32768] bf16
                       float* __restrict__ W4v,           // [192][512][4] fp32
                       float* __restrict__ W5v)           // [128][512][4] fp32
{
    int f = blockIdx.x * 256 + threadIdx.x;
    if (f < NPV_WP) {
        int l = f >> 15, r = f & 32767;
        int n = r >> 6, kq = r & 63;                 // k0 = kq*8
        const float* W = (l == 0) ? W1 : (l == 1) ? W2 : W3;
        const float* src = W + n * 512 + kq * 8;
        int s = kq >> 2, q4 = kq & 3;
        int wv = n >> 6, jj = (n >> 4) & 3, i16 = n & 15;
        int lane = q4 * 16 + i16;
        unsigned w[4];
        #pragma unroll
        for (int h = 0; h < 4; ++h)
            w[h] = (unsigned)f2bf(src[h * 2]) | ((unsigned)f2bf(src[h * 2 + 1]) << 16);
        *(u32x4*)(Wp + (size_t)l * 262144 + ((((wv * 16 + s) * 4 + jj) * 64 + lane) << 3))
            = (u32x4){w[0], w[1], w[2], w[3]};
    } else if (f < NPV_WP + NPV_W0P) {
        int g = f - NPV_WP;
        int n = g >> 3, kq = g & 7;
        int s = kq >> 2, q4 = kq & 3;
        int wv = n >> 6, jj = (n >> 4) & 3, i16 = n & 15;
        int lane = q4 * 16 + i16;
        unsigned w[4];
        #pragma unroll
        for (int h = 0; h < 4; ++h) {
            int k0 = kq * 8 + h * 2, k1 = k0 + 1;
            float f0 = (k0 < 52) ? W0[n * 52 + k0] : 0.f;
            float f1 = (k1 < 52) ? W0[n * 52 + k1] : 0.f;
            w[h] = (unsigned)f2bf(f0) | ((unsigned)f2bf(f1) << 16);
        }
        *(u32x4*)(W0p + ((((wv * 2 + s) * 4 + jj) * 64 + lane) << 3))
            = (u32x4){w[0], w[1], w[2], w[3]};
    } else if (f < NPV_WP + NPV_W0P + NPV_W4) {
        int g = f - (NPV_WP + NPV_W0P);
        int o = g / 192, kb = g % 192;
        float4 w = *(const float4*)(W4 + (size_t)o * 768 + kb * 4);
        *(float4*)(W4v + (size_t)kb * 2048 + o * 4) = w;
    } else {
        int g = f - (NPV_WP + NPV_W0P + NPV_W4);
        int o = g >> 7, kb = g & 127;
        float4 w = *(const float4*)(W5 + (size_t)o * 512 + kb * 4);
        *(float4*)(W5v + (size_t)kb * 2048 + o * 4) = w;
    }
}

// ---------------- h-store epilogue: bias + relu + bf16 LDS write ----
// Granule-column-major target: byte = (col>>3)*1024 + (row ^ ((col>>3)&7))*16
//                                    + (col&7)*2.
// DPP quad_perm swap on f32, then v_cvt_pk_bf16_f32 packs (col, col+1) into
// one dword; even lanes write ds_write_b32.
__device__ __forceinline__ void store_h(const f32x4 (&acc)[4][4], const float* __restrict__ bl,
                                        unsigned short* hbuf, int wave, int i16, int q4, int lane)
{
    char* base = (char*)hbuf;
    #pragma unroll
    for (int j = 0; j < 4; ++j) {
        int col = (wave * 4 + j) * 16 + i16;
        int g = col >> 3;
        int e = g & 7;
        float bb = bl[col];
        char* colbase = base + g * 1024 + ((col & 7) << 1);
        #pragma unroll
        for (int mt = 0; mt < 4; ++mt) {
            #pragma unroll
            for (int r = 0; r < 4; ++r) {
                int row = mt * 16 + q4 * 4 + r;
                float v = fmaxf(acc[mt][j][r] + bb, 0.f);
                int vi = __float_as_int(v);
                // quad_perm [1,0,3,2]: each lane gets partner (lane^1)'s f32
                int swi = __builtin_amdgcn_update_dpp(0, vi, 0xB1, 0xF, 0xF, true);
                if ((lane & 1) == 0) {
                    unsigned pk;
                    asm("v_cvt_pk_bf16_f32 %0, %1, %2" : "=v"(pk) : "v"(vi), "v"(swi));
                    int slot = row ^ e;
                    *(unsigned*)(colbase + slot * 16) = pk;
                }
            }
        }
    }
}

#define CLUSTER(AV0, AV1, AV2, AV3, BV, JJ)                                              \
    __builtin_amdgcn_s_setprio(1);                                                      \
    acc[0][JJ] = __builtin_amdgcn_mfma_f32_16x16x32_bf16(AV0, BV, acc[0][JJ], 0, 0, 0); \
    acc[1][JJ] = __builtin_amdgcn_mfma_f32_16x16x32_bf16(AV1, BV, acc[1][JJ], 0, 0, 0); \
    acc[2][JJ] = __builtin_amdgcn_mfma_f32_16x16x32_bf16(AV2, BV, acc[2][JJ], 0, 0, 0); \
    acc[3][JJ] = __builtin_amdgcn_mfma_f32_16x16x32_bf16(AV3, BV, acc[3][JJ], 0, 0, 0); \
    __builtin_amdgcn_s_setprio(0);                                                      \
    __builtin_amdgcn_sched_barrier(0);

// ---------------- fused layers 0..3 ----------------
// One block per (b,p): 64 pair-rows. h tile 64x512 bf16, DOUBLE-BUFFERED in
// LDS: layer l reads hsm[l&1], writes hsm[(l+1)&1]. Granule-column-major
// within each buffer: [g=k>>3][slot=row^(g&7)][8 shorts].
// 8 waves; wave w computes cols [w*64, w*64+64): acc = 4 (row tiles) x 4 (col tiles).
__global__ __launch_bounds__(512, 2) void k_fused(
    const float* __restrict__ x,
    const unsigned short* __restrict__ Wp,
    const unsigned short* __restrict__ W0p,
    const float* __restrict__ b0, const float* __restrict__ b1,
    const float* __restrict__ b2, const float* __restrict__ b3,
    float* __restrict__ P)
{
    __shared__ __align__(16) unsigned short hsm[2 * 64 * 512];   // 128 KiB (2 bufs)
    __shared__ __align__(16) unsigned short xs[8 * 64 * 8];      // 8 KiB (x-pair tile)
    int t = threadIdx.x;
    int blk = blockIdx.x;
    int b = blk >> 6, p = blk & 63;

    // ---- stage xs: [g(8)][slot=row^g][8] bf16 of [x[b,row,:26] | x[b,p,:26] | 0] ----
    {
        int row = t >> 3, gr = t & 7;
        const float* xq = x + (size_t)(b * 64 + row) * 26;
        const float* xp = x + (size_t)(b * 64 + p) * 26;
        unsigned w[4];
        #pragma unroll
        for (int h = 0; h < 4; ++h) {
            int k0 = gr * 8 + h * 2;
            int k1 = k0 + 1;
            float f0 = (k0 < 26) ? xq[k0] : (k0 < 52 ? xp[k0 - 26] : 0.f);
            float f1 = (k1 < 26) ? xq[k1] : (k1 < 52 ? xp[k1 - 26] : 0.f);
            w[h] = (unsigned)f2bf(f0) | ((unsigned)f2bf(f1) << 16);
        }
        *(u32x4*)((char*)xs + gr * 1024 + ((row ^ gr) << 4)) = (u32x4){w[0], w[1], w[2], w[3]};
    }

    int wave = t >> 6, lane = t & 63;
    int i16 = lane & 15, q4 = lane >> 4;

    f32x4 acc[4][4];
    bf16x8 X0, X1, X2, X3, Y0, Y1, Y2, Y3;   // B stream dbuf, live across layers

    // per-wave B base for packed weights (layer stride 262144 shorts)
    const unsigned short* Bb0base = Wp + wave * 32768 + lane * 8;

    __syncthreads();   // xs ready                                   [barrier 1]

    // ---- layer 0: h0 = relu([x_q|x_p] @ W0^T + b0), K=64 padded ----
    {
        #pragma unroll
        for (int mt = 0; mt < 4; ++mt)
            #pragma unroll
            for (int j = 0; j < 4; ++j)
                acc[mt][j] = (f32x4){0.f, 0.f, 0.f, 0.f};
        const unsigned short* Bw0 = W0p + wave * 4096 + lane * 8;
        const char* xb = (const char*)xs;
        #pragma unroll
        for (int s = 0; s < 2; ++s) {
            bf16x8 bfr[4];
            #pragma unroll
            for (int j = 0; j < 4; ++j)
                bfr[j] = *(const bf16x8*)(Bw0 + s * 2048 + j * 512);
            int g = s * 4 + q4;
            const char* A0 = xb + g * 1024 + ((i16 ^ g) << 4);
            #pragma unroll
            for (int mt = 0; mt < 4; ++mt) {
                bf16x8 a = *(const bf16x8*)(A0 + mt * 256);
                #pragma unroll
                for (int j = 0; j < 4; ++j)
                    acc[mt][j] = __builtin_amdgcn_mfma_f32_16x16x32_bf16(a, bfr[j], acc[mt][j], 0, 0, 0);
            }
        }
        // prefetch layer-1 B(0)/B(1) NOW; latency hides under store_h below
        X0 = *(const bf16x8*)(Bb0base);
        X1 = *(const bf16x8*)(Bb0base + 512);
        X2 = *(const bf16x8*)(Bb0base + 1024);
        X3 = *(const bf16x8*)(Bb0base + 1536);
        Y0 = *(const bf16x8*)(Bb0base + 2048);
        Y1 = *(const bf16x8*)(Bb0base + 2560);
        Y2 = *(const bf16x8*)(Bb0base + 3072);
        Y3 = *(const bf16x8*)(Bb0base + 3584);
        store_h(acc, b0, hsm, wave, i16, q4, lane);   // h0 -> buf0
    }
    __syncthreads();   // buf0 ready                                 [barrier 2]

    // ---- layers 1..3: X/Y B-dbuf (2-step-ahead), A even/odd dbuf (1 ahead) ----
    int A_even = (q4 << 10) + ((i16 ^ q4) << 4);
    int A_odd  = 4096 + (A_even ^ 64);

    #pragma unroll 1
    for (int l = 0; l < 3; ++l) {
        const float* bl = (l == 0) ? b1 : (l == 1) ? b2 : b3;
        const unsigned short* Bb = Bb0base + (size_t)l * 262144;
        const char* hb = (const char*)hsm + (l & 1) * 65536;   // read buffer
        const char* hbe = hb + A_even;          // even-step A base
        const char* hbo = hb + A_odd;           // odd-step A base

        #pragma unroll
        for (int mt = 0; mt < 4; ++mt)
            #pragma unroll
            for (int j = 0; j < 4; ++j)
                acc[mt][j] = (f32x4){0.f, 0.f, 0.f, 0.f};

        // A(0)
        bf16x8 aE0 = *(const bf16x8*)(hbe);
        bf16x8 aE1 = *(const bf16x8*)(hbe + 256);
        bf16x8 aE2 = *(const bf16x8*)(hbe + 512);
        bf16x8 aE3 = *(const bf16x8*)(hbe + 768);
        bf16x8 aO0, aO1, aO2, aO3;

        #pragma unroll 1
        for (int s = 0; s < 16; s += 2) {
            // ===== even step s: consume aE*, X*; reload X = B(s+2), aO = A(s+1) =====
            {
                const unsigned short* BX = Bb + ((s + 2 < 16) ? (s + 2) : 14) * 2048;
                const char* po = hbo + (s << 12);      // A(s+1)
                CLUSTER(aE0, aE1, aE2, aE3, X0, 0)
                X0 = *(const bf16x8*)(BX);
                aO0 = *(const bf16x8*)(po);
                aO1 = *(const bf16x8*)(po + 256);
                CLUSTER(aE0, aE1, aE2, aE3, X1, 1)
                X1 = *(const bf16x8*)(BX + 512);
                aO2 = *(const bf16x8*)(po + 512);
                aO3 = *(const bf16x8*)(po + 768);
                CLUSTER(aE0, aE1, aE2, aE3, X2, 2)
                X2 = *(const bf16x8*)(BX + 1024);
                CLUSTER(aE0, aE1, aE2, aE3, X3, 3)
                X3 = *(const bf16x8*)(BX + 1536);
            }
            // ===== odd step s+1: consume aO*, Y*; reload Y = B(s+3), aE = A(s+2) =====
            {
                const unsigned short* BY = Bb + ((s + 3 < 16) ? (s + 3) : 15) * 2048;
                const char* pe = hbe + ((s + 2 < 16 ? s + 2 : 14) << 12);   // A(s+2)
                CLUSTER(aO0, aO1, aO2, aO3, Y0, 0)
                Y0 = *(const bf16x8*)(BY);
                aE0 = *(const bf16x8*)(pe);
                aE1 = *(const bf16x8*)(pe + 256);
                CLUSTER(aO0, aO1, aO2, aO3, Y1, 1)
                Y1 = *(const bf16x8*)(BY + 512);
                aE2 = *(const bf16x8*)(pe + 512);
                aE3 = *(const bf16x8*)(pe + 768);
                CLUSTER(aO0, aO1, aO2, aO3, Y2, 2)
                Y2 = *(const bf16x8*)(BY + 1024);
                CLUSTER(aO0, aO1, aO2, aO3, Y3, 3)
                Y3 = *(const bf16x8*)(BY + 1536);
            }
        }

        if (l < 2) {
            // prefetch NEXT layer's B(0)/B(1) before the epilogue; its L2
            // latency hides under store_h's VALU work (tail reloads above
            // were dead and are simply overwritten here)
            const unsigned short* Bn = Bb + 262144;
            X0 = *(const bf16x8*)(Bn);
            X1 = *(const bf16x8*)(Bn + 512);
            X2 = *(const bf16x8*)(Bn + 1024);
            X3 = *(const bf16x8*)(Bn + 1536);
            Y0 = *(const bf16x8*)(Bn + 2048);
            Y1 = *(const bf16x8*)(Bn + 2560);
            Y2 = *(const bf16x8*)(Bn + 3072);
            Y3 = *(const bf16x8*)(Bn + 3584);
            // write h_{l+1} into the OTHER buffer: no read-hazard barrier needed
            store_h(acc, bl, (unsigned short*)((char*)hsm + ((l + 1) & 1) * 65536),
                    wave, i16, q4, lane);
            __syncthreads();   // next buffer ready     [barriers 3,4]
        } else {
            // layer 3: bias + relu + sum over 64 rows -> per-block partial P[blk][col]
            #pragma unroll
            for (int j = 0; j < 4; ++j) {
                int col = (wave * 4 + j) * 16 + i16;
                float bb = bl[col];
                float sum = 0.f;
                #pragma unroll
                for (int mt = 0; mt < 4; ++mt)
                    #pragma unroll
                    for (int r = 0; r < 4; ++r)
                        sum += fmaxf(acc[mt][j][r] + bb, 0.f);
                sum += __shfl_xor(sum, 16);
                sum += __shfl_xor(sum, 32);
                if (q4 == 0) P[(size_t)blk * 512 + col] = sum;
            }
        }
    }
}

// ---------------- tail: reduce P + layers 4,5,6 + log_softmax ----
__global__ __launch_bounds__(1024) void k_tail(
    const float* __restrict__ P, const float* __restrict__ qst,
    const float* __restrict__ W4v, const float* __restrict__ b4,
    const float* __restrict__ W5v, const float* __restrict__ b5,
    const float* __restrict__ W6, const float* __restrict__ b6,
    float* __restrict__ out)
{
    int b = blockIdx.x, t = threadIdx.x;
    __shared__ __align__(16) float z[768];
    __shared__ __align__(16) float ps[1024];
    __shared__ __align__(16) float h4[512];
    __shared__ float h5[512];
    __shared__ float logits[28];
    __shared__ float red[2];

    if (t < 512) {     // reduce the 64 per-(b,p)-block partials
        float s = 0.f;
        const float* Pb = P + (size_t)b * 64 * 512 + t;
        #pragma unroll 8
        for (int c = 0; c < 64; ++c) s += Pb[c * 512];
        z[t] = s;
    } else if (t < 768) {
        z[t] = qst[b * 256 + (t - 512)];
    }
    __syncthreads();
    {   // layer 4: 768 -> 512, 2-way k-split per output
        int o = t & 511, hf = t >> 9;
        float acc = 0.f;
        const float4* Wv = (const float4*)W4v;
        const float4* z4 = (const float4*)z;
        #pragma unroll 4
        for (int kb = hf * 96; kb < hf * 96 + 96; ++kb) {
            float4 w = Wv[kb * 512 + o];
            float4 zz = z4[kb];
            acc = fmaf(w.x, zz.x, acc);
            acc = fmaf(w.y, zz.y, acc);
            acc = fmaf(w.z, zz.z, acc);
            acc = fmaf(w.w, zz.w, acc);
        }
        ps[t] = acc;
    }
    __syncthreads();
    if (t < 512) h4[t] = fmaxf(ps[t] + ps[t + 512] + b4[t], 0.f);
    __syncthreads();
    {   // layer 5: 512 -> 512, 2-way k-split per output
        int o = t & 511, hf = t >> 9;
        float acc = 0.f;
        const float4* Wv = (const float4*)W5v;
        const float4* h44 = (const float4*)h4;
        #pragma unroll 4
        for (int kb = hf * 64; kb < hf * 64 + 64; ++kb) {
            float4 w = Wv[kb * 512 + o];
            float4 hh = h44[kb];
            acc = fmaf(w.x, hh.x, acc);
            acc = fmaf(w.y, hh.y, acc);
            acc = fmaf(w.z, hh.z, acc);
            acc = fmaf(w.w, hh.w, acc);
        }
        ps[t] = acc;
    }
    __syncthreads();
    if (t < 512) h5[t] = fmaxf(ps[t] + ps[t + 512] + b5[t], 0.f);
    __syncthreads();
    {   // layer 6: 512 -> 28 (32 lanes per output)
        int o = t >> 5, c = t & 31;
        if (o < 28) {
            float acc = 0.f;
            for (int k = c; k < 512; k += 32) acc = fmaf(W6[o * 512 + k], h5[k], acc);
            acc += __shfl_xor(acc, 1);
            acc += __shfl_xor(acc, 2);
            acc += __shfl_xor(acc, 4);
            acc += __shfl_xor(acc, 8);
            acc += __shfl_xor(acc, 16);
            if (c == 0) logits[o] = acc + b6[o];
        }
    }
    __syncthreads();
    if (t == 0) {
        float mx = -1e30f;
        for (int cc = 0; cc < 28; ++cc) mx = fmaxf(mx, logits[cc]);
        float se = 0.f;
        for (int cc = 0; cc < 28; ++cc) se += expf(logits[cc] - mx);
        red[0] = mx; red[1] = logf(se);
    }
    __syncthreads();
    if (t < 28) out[b * 28 + t] = logits[t] - red[0] - red[1];
}

extern "C" void kernel_launch(void* const* d_in, const int* in_sizes, int n_in,
                              void* d_out, int out_size, void* d_ws, size_t ws_size,
                              hipStream_t stream)
{
    const float* x   = (const float*)d_in[0];
    const float* qst = (const float*)d_in[1];
    const float* W0  = (const float*)d_in[2];
    const float* b0  = (const float*)d_in[3];
    const float* W1  = (const float*)d_in[4];
    const float* b1  = (const float*)d_in[5];
    const float* W2  = (const float*)d_in[6];
    const float* b2  = (const float*)d_in[7];
    const float* W3  = (const float*)d_in[8];
    const float* b3  = (const float*)d_in[9];
    const float* W4  = (const float*)d_in[10];
    const float* b4  = (const float*)d_in[11];
    const float* W5  = (const float*)d_in[12];
    const float* b5  = (const float*)d_in[13];
    const float* W6  = (const float*)d_in[14];
    const float* b6  = (const float*)d_in[15];
    float* out = (float*)d_out;

    char* ws = (char*)d_ws;
    unsigned short* Wp  = (unsigned short*)(ws);             // 1.5 MiB
    unsigned short* W0p = (unsigned short*)(ws + 1572864);   // 64 KiB
    float*          W4v = (float*)(ws + 1638400);            // 1.5 MiB
    float*          W5v = (float*)(ws + 3211264);            // 1 MiB
    float*          P   = (float*)(ws + 4259840);            // 4 MiB partials

    k_prep <<<NPV_TOTAL / 256, 256, 0, stream>>>(W1, W2, W3, W0, W4, W5,
                                                 Wp, W0p, W4v, W5v);
    k_fused<<<2048, 512, 0, stream>>>(x, Wp, W0p, b0, b1, b2, b3, P);
    k_tail <<<32, 1024, 0, stream>>>(P, qst, W4v, b4, W5v, b5, W6, b6, out);
}

// Round 15
// 321.354 us; speedup vs baseline: 3.3472x; 1.0024x over previous
//
#include <hip/hip_runtime.h>
#include <math.h>

// Relational Network fused pipeline for MI355X (gfx950).
// B=32, D=64, K=26, QST=256, G=[512x6, 28], AGG at layer 4.
//
// Round 20 changes vs round 19 (best: 322.1us, k_fused 232.6us, VGPR 120):
//  - SINGLE-VARIABLE A/B: remove sched_barrier(0) from the CLUSTER macro.
//    m141 (learn_hip) measured sched_barrier(0) order-pinning costing 42%
//    on the m97 GEMM ("defeats compiler's own scheduling"); our fences were
//    inherited from the M=128 spill-fighting era (R13) and forbid the
//    compiler from hoisting A-ds_reads / B-flat-loads / counted waitcnts
//    across cluster boundaries. At M=64 / 120 arch regs the spill risk that
//    motivated them is gone. setprio retained (present in all baselines).
//  - Everything else byte-identical to round 19: hsm double-buffer (4
//    barriers/block), next-layer B prefetch before store_h, vectorized
//    k_prep, 1024-thread k_tail.
//  - Tripwire: WRITE_SIZE > 20MB (load-batching spill) or dur regression
//    -> restore fences, schedule is compiler-optimal, pivot to periphery.

typedef __attribute__((ext_vector_type(8))) short bf16x8;   // 8 bf16 in 4 VGPRs
typedef __attribute__((ext_vector_type(4))) float f32x4;    // MFMA 16x16 accumulator
typedef __attribute__((ext_vector_type(4))) unsigned int u32x4;

__device__ __forceinline__ unsigned short f2bf(float f) {
    union { float f; unsigned u; } x; x.f = f;
    unsigned r = x.u + 0x7fffu + ((x.u >> 16) & 1u);   // RNE
    return (unsigned short)(r >> 16);
}

// ---------------- pack / transpose weights (vectorized) ----------------
// Wp layout per layer: [wave(8)][s(16)][jj(4)][lane(64)][j(8)] bf16,
//   value = W[n][k], n = (wave*4+jj)*16 + (lane&15), k = s*32 + (lane>>4)*8 + j.
// W0p: same with s(2) over padded K=64 (k >= 52 -> 0).
// W4v/W5v: fp32 [k/4][512 out][4] so k_tail threads stream float4.
#define NPV_WP   98304            // 3 * 512 * 64   (8 bf16/thread)
#define NPV_W0P  4096             // 512 * 8        (8 bf16/thread)
#define NPV_W4   98304            // 768*512/4      (4 f32/thread)
#define NPV_W5   65536            // 512*512/4
#define NPV_TOTAL (NPV_WP + NPV_W0P + NPV_W4 + NPV_W5)   // 266240 = 1040*256
__global__ void k_prep(const float* __restrict__ W1, const float* __restrict__ W2,
                       const float* __restrict__ W3, const float* __restrict__ W0,
                       const float* __restrict__ W4, const float* __restrict__ W5,
                       unsigned short* __restrict__ Wp,   // [3][262144] bf16
                       unsigned short* __restrict__ W0p,  // [32768] bf16
                       float* __restrict__ W4v,           // [192][512][4] fp32
                       float* __restrict__ W5v)           // [128][512][4] fp32
{
    int f = blockIdx.x * 256 + threadIdx.x;
    if (f < NPV_WP) {
        int l = f >> 15, r = f & 32767;
        int n = r >> 6, kq = r & 63;                 // k0 = kq*8
        const float* W = (l == 0) ? W1 : (l == 1) ? W2 : W3;
        const float* src = W + n * 512 + kq * 8;
        int s = kq >> 2, q4 = kq & 3;
        int wv = n >> 6, jj = (n >> 4) & 3, i16 = n & 15;
        int lane = q4 * 16 + i16;
        unsigned w[4];
        #pragma unroll
        for (int h = 0; h < 4; ++h)
            w[h] = (unsigned)f2bf(src[h * 2]) | ((unsigned)f2bf(src[h * 2 + 1]) << 16);
        *(u32x4*)(Wp + (size_t)l * 262144 + ((((wv * 16 + s) * 4 + jj) * 64 + lane) << 3))
            = (u32x4){w[0], w[1], w[2], w[3]};
    } else if (f < NPV_WP + NPV_W0P) {
        int g = f - NPV_WP;
        int n = g >> 3, kq = g & 7;
        int s = kq >> 2, q4 = kq & 3;
        int wv = n >> 6, jj = (n >> 4) & 3, i16 = n & 15;
        int lane = q4 * 16 + i16;
        unsigned w[4];
        #pragma unroll
        for (int h = 0; h < 4; ++h) {
            int k0 = kq * 8 + h * 2, k1 = k0 + 1;
            float f0 = (k0 < 52) ? W0[n * 52 + k0] : 0.f;
            float f1 = (k1 < 52) ? W0[n * 52 + k1] : 0.f;
            w[h] = (unsigned)f2bf(f0) | ((unsigned)f2bf(f1) << 16);
        }
        *(u32x4*)(W0p + ((((wv * 2 + s) * 4 + jj) * 64 + lane) << 3))
            = (u32x4){w[0], w[1], w[2], w[3]};
    } else if (f < NPV_WP + NPV_W0P + NPV_W4) {
        int g = f - (NPV_WP + NPV_W0P);
        int o = g / 192, kb = g % 192;
        float4 w = *(const float4*)(W4 + (size_t)o * 768 + kb * 4);
        *(float4*)(W4v + (size_t)kb * 2048 + o * 4) = w;
    } else {
        int g = f - (NPV_WP + NPV_W0P + NPV_W4);
        int o = g >> 7, kb = g & 127;
        float4 w = *(const float4*)(W5 + (size_t)o * 512 + kb * 4);
        *(float4*)(W5v + (size_t)kb * 2048 + o * 4) = w;
    }
}

// ---------------- h-store epilogue: bias + relu + bf16 LDS write ----
// Granule-column-major target: byte = (col>>3)*1024 + (row ^ ((col>>3)&7))*16
//                                    + (col&7)*2.
// DPP quad_perm swap on f32, then v_cvt_pk_bf16_f32 packs (col, col+1) into
// one dword; even lanes write ds_write_b32.
__device__ __forceinline__ void store_h(const f32x4 (&acc)[4][4], const float* __restrict__ bl,
                                        unsigned short* hbuf, int wave, int i16, int q4, int lane)
{
    char* base = (char*)hbuf;
    #pragma unroll
    for (int j = 0; j < 4; ++j) {
        int col = (wave * 4 + j) * 16 + i16;
        int g = col >> 3;
        int e = g & 7;
        float bb = bl[col];
        char* colbase = base + g * 1024 + ((col & 7) << 1);
        #pragma unroll
        for (int mt = 0; mt < 4; ++mt) {
            #pragma unroll
            for (int r = 0; r < 4; ++r) {
                int row = mt * 16 + q4 * 4 + r;
                float v = fmaxf(acc[mt][j][r] + bb, 0.f);
                int vi = __float_as_int(v);
                // quad_perm [1,0,3,2]: each lane gets partner (lane^1)'s f32
                int swi = __builtin_amdgcn_update_dpp(0, vi, 0xB1, 0xF, 0xF, true);
                if ((lane & 1) == 0) {
                    unsigned pk;
                    asm("v_cvt_pk_bf16_f32 %0, %1, %2" : "=v"(pk) : "v"(vi), "v"(swi));
                    int slot = row ^ e;
                    *(unsigned*)(colbase + slot * 16) = pk;
                }
            }
        }
    }
}

// No sched_barrier here (round 20): let the compiler interleave loads and
// counted waitcnts across cluster boundaries (m141: pinning cost 42%).
#define CLUSTER(AV0, AV1, AV2, AV3, BV, JJ)                                              \
    __builtin_amdgcn_s_setprio(1);                                                      \
    acc[0][JJ] = __builtin_amdgcn_mfma_f32_16x16x32_bf16(AV0, BV, acc[0][JJ], 0, 0, 0); \
    acc[1][JJ] = __builtin_amdgcn_mfma_f32_16x16x32_bf16(AV1, BV, acc[1][JJ], 0, 0, 0); \
    acc[2][JJ] = __builtin_amdgcn_mfma_f32_16x16x32_bf16(AV2, BV, acc[2][JJ], 0, 0, 0); \
    acc[3][JJ] = __builtin_amdgcn_mfma_f32_16x16x32_bf16(AV3, BV, acc[3][JJ], 0, 0, 0); \
    __builtin_amdgcn_s_setprio(0);

// ---------------- fused layers 0..3 ----------------
// One block per (b,p): 64 pair-rows. h tile 64x512 bf16, DOUBLE-BUFFERED in
// LDS: layer l reads hsm[l&1], writes hsm[(l+1)&1]. Granule-column-major
// within each buffer: [g=k>>3][slot=row^(g&7)][8 shorts].
// 8 waves; wave w computes cols [w*64, w*64+64): acc = 4 (row tiles) x 4 (col tiles).
__global__ __launch_bounds__(512, 2) void k_fused(
    const float* __restrict__ x,
    const unsigned short* __restrict__ Wp,
    const unsigned short* __restrict__ W0p,
    const float* __restrict__ b0, const float* __restrict__ b1,
    const float* __restrict__ b2, const float* __restrict__ b3,
    float* __restrict__ P)
{
    __shared__ __align__(16) unsigned short hsm[2 * 64 * 512];   // 128 KiB (2 bufs)
    __shared__ __align__(16) unsigned short xs[8 * 64 * 8];      // 8 KiB (x-pair tile)
    int t = threadIdx.x;
    int blk = blockIdx.x;
    int b = blk >> 6, p = blk & 63;

    // ---- stage xs: [g(8)][slot=row^g][8] bf16 of [x[b,row,:26] | x[b,p,:26] | 0] ----
    {
        int row = t >> 3, gr = t & 7;
        const float* xq = x + (size_t)(b * 64 + row) * 26;
        const float* xp = x + (size_t)(b * 64 + p) * 26;
        unsigned w[4];
        #pragma unroll
        for (int h = 0; h < 4; ++h) {
            int k0 = gr * 8 + h * 2;
            int k1 = k0 + 1;
            float f0 = (k0 < 26) ? xq[k0] : (k0 < 52 ? xp[k0 - 26] : 0.f);
            float f1 = (k1 < 26) ? xq[k1] : (k1 < 52 ? xp[k1 - 26] : 0.f);
            w[h] = (unsigned)f2bf(f0) | ((unsigned)f2bf(f1) << 16);
        }
        *(u32x4*)((char*)xs + gr * 1024 + ((row ^ gr) << 4)) = (u32x4){w[0], w[1], w[2], w[3]};
    }

    int wave = t >> 6, lane = t & 63;
    int i16 = lane & 15, q4 = lane >> 4;

    f32x4 acc[4][4];
    bf16x8 X0, X1, X2, X3, Y0, Y1, Y2, Y3;   // B stream dbuf, live across layers

    // per-wave B base for packed weights (layer stride 262144 shorts)
    const unsigned short* Bb0base = Wp + wave * 32768 + lane * 8;

    __syncthreads();   // xs ready                                   [barrier 1]

    // ---- layer 0: h0 = relu([x_q|x_p] @ W0^T + b0), K=64 padded ----
    {
        #pragma unroll
        for (int mt = 0; mt < 4; ++mt)
            #pragma unroll
            for (int j = 0; j < 4; ++j)
                acc[mt][j] = (f32x4){0.f, 0.f, 0.f, 0.f};
        const unsigned short* Bw0 = W0p + wave * 4096 + lane * 8;
        const char* xb = (const char*)xs;
        #pragma unroll
        for (int s = 0; s < 2; ++s) {
            bf16x8 bfr[4];
            #pragma unroll
            for (int j = 0; j < 4; ++j)
                bfr[j] = *(const bf16x8*)(Bw0 + s * 2048 + j * 512);
            int g = s * 4 + q4;
            const char* A0 = xb + g * 1024 + ((i16 ^ g) << 4);
            #pragma unroll
            for (int mt = 0; mt < 4; ++mt) {
                bf16x8 a = *(const bf16x8*)(A0 + mt * 256);
                #pragma unroll
                for (int j = 0; j < 4; ++j)
                    acc[mt][j] = __builtin_amdgcn_mfma_f32_16x16x32_bf16(a, bfr[j], acc[mt][j], 0, 0, 0);
            }
        }
        // prefetch layer-1 B(0)/B(1) NOW; latency hides under store_h below
        X0 = *(const bf16x8*)(Bb0base);
        X1 = *(const bf16x8*)(Bb0base + 512);
        X2 = *(const bf16x8*)(Bb0base + 1024);
        X3 = *(const bf16x8*)(Bb0base + 1536);
        Y0 = *(const bf16x8*)(Bb0base + 2048);
        Y1 = *(const bf16x8*)(Bb0base + 2560);
        Y2 = *(const bf16x8*)(Bb0base + 3072);
        Y3 = *(const bf16x8*)(Bb0base + 3584);
        store_h(acc, b0, hsm, wave, i16, q4, lane);   // h0 -> buf0
    }
    __syncthreads();   // buf0 ready                                 [barrier 2]

    // ---- layers 1..3: X/Y B-dbuf (2-step-ahead), A even/odd dbuf (1 ahead) ----
    int A_even = (q4 << 10) + ((i16 ^ q4) << 4);
    int A_odd  = 4096 + (A_even ^ 64);

    #pragma unroll 1
    for (int l = 0; l < 3; ++l) {
        const float* bl = (l == 0) ? b1 : (l == 1) ? b2 : b3;
        const unsigned short* Bb = Bb0base + (size_t)l * 262144;
        const char* hb = (const char*)hsm + (l & 1) * 65536;   // read buffer
        const char* hbe = hb + A_even;          // even-step A base
        const char* hbo = hb + A_odd;           // odd-step A base

        #pragma unroll
        for (int mt = 0; mt < 4; ++mt)
            #pragma unroll
            for (int j = 0; j < 4; ++j)
                acc[mt][j] = (f32x4){0.f, 0.f, 0.f, 0.f};

        // A(0)
        bf16x8 aE0 = *(const bf16x8*)(hbe);
        bf16x8 aE1 = *(const bf16x8*)(hbe + 256);
        bf16x8 aE2 = *(const bf16x8*)(hbe + 512);
        bf16x8 aE3 = *(const bf16x8*)(hbe + 768);
        bf16x8 aO0, aO1, aO2, aO3;

        #pragma unroll 1
        for (int s = 0; s < 16; s += 2) {
            // ===== even step s: consume aE*, X*; reload X = B(s+2), aO = A(s+1) =====
            {
                const unsigned short* BX = Bb + ((s + 2 < 16) ? (s + 2) : 14) * 2048;
                const char* po = hbo + (s << 12);      // A(s+1)
                CLUSTER(aE0, aE1, aE2, aE3, X0, 0)
                X0 = *(const bf16x8*)(BX);
                aO0 = *(const bf16x8*)(po);
                aO1 = *(const bf16x8*)(po + 256);
                CLUSTER(aE0, aE1, aE2, aE3, X1, 1)
                X1 = *(const bf16x8*)(BX + 512);
                aO2 = *(const bf16x8*)(po + 512);
                aO3 = *(const bf16x8*)(po + 768);
                CLUSTER(aE0, aE1, aE2, aE3, X2, 2)
                X2 = *(const bf16x8*)(BX + 1024);
                CLUSTER(aE0, aE1, aE2, aE3, X3, 3)
                X3 = *(const bf16x8*)(BX + 1536);
            }
            // ===== odd step s+1: consume aO*, Y*; reload Y = B(s+3), aE = A(s+2) =====
            {
                const unsigned short* BY = Bb + ((s + 3 < 16) ? (s + 3) : 15) * 2048;
                const char* pe = hbe + ((s + 2 < 16 ? s + 2 : 14) << 12);   // A(s+2)
                CLUSTER(aO0, aO1, aO2, aO3, Y0, 0)
                Y0 = *(const bf16x8*)(BY);
                aE0 = *(const bf16x8*)(pe);
                aE1 = *(const bf16x8*)(pe + 256);
                CLUSTER(aO0, aO1, aO2, aO3, Y1, 1)
                Y1 = *(const bf16x8*)(BY + 512);
                aE2 = *(const bf16x8*)(pe + 512);
                aE3 = *(const bf16x8*)(pe + 768);
                CLUSTER(aO0, aO1, aO2, aO3, Y2, 2)
                Y2 = *(const bf16x8*)(BY + 1024);
                CLUSTER(aO0, aO1, aO2, aO3, Y3, 3)
                Y3 = *(const bf16x8*)(BY + 1536);
            }
        }

        if (l < 2) {
            // prefetch NEXT layer's B(0)/B(1) before the epilogue; its L2
            // latency hides under store_h's VALU work (tail reloads above
            // were dead and are simply overwritten here)
            const unsigned short* Bn = Bb + 262144;
            X0 = *(const bf16x8*)(Bn);
            X1 = *(const bf16x8*)(Bn + 512);
            X2 = *(const bf16x8*)(Bn + 1024);
            X3 = *(const bf16x8*)(Bn + 1536);
            Y0 = *(const bf16x8*)(Bn + 2048);
            Y1 = *(const bf16x8*)(Bn + 2560);
            Y2 = *(const bf16x8*)(Bn + 3072);
            Y3 = *(const bf16x8*)(Bn + 3584);
            // write h_{l+1} into the OTHER buffer: no read-hazard barrier needed
            store_h(acc, bl, (unsigned short*)((char*)hsm + ((l + 1) & 1) * 65536),
                    wave, i16, q4, lane);
            __syncthreads();   // next buffer ready     [barriers 3,4]
        } else {
            // layer 3: bias + relu + sum over 64 rows -> per-block partial P[blk][col]
            #pragma unroll
            for (int j = 0; j < 4; ++j) {
                int col = (wave * 4 + j) * 16 + i16;
                float bb = bl[col];
                float sum = 0.f;
                #pragma unroll
                for (int mt = 0; mt < 4; ++mt)
                    #pragma unroll
                    for (int r = 0; r < 4; ++r)
                        sum += fmaxf(acc[mt][j][r] + bb, 0.f);
                sum += __shfl_xor(sum, 16);
                sum += __shfl_xor(sum, 32);
                if (q4 == 0) P[(size_t)blk * 512 + col] = sum;
            }
        }
    }
}

// ---------------- tail: reduce P + layers 4,5,6 + log_softmax ----
__global__ __launch_bounds__(1024) void k_tail(
    const float* __restrict__ P, const float* __restrict__ qst,
    const float* __restrict__ W4v, const float* __restrict__ b4,
    const float* __restrict__ W5v, const float* __restrict__ b5,
    const float* __restrict__ W6, const float* __restrict__ b6,
    float* __restrict__ out)
{
    int b = blockIdx.x, t = threadIdx.x;
    __shared__ __align__(16) float z[768];
    __shared__ __align__(16) float ps[1024];
    __shared__ __align__(16) float h4[512];
    __shared__ float h5[512];
    __shared__ float logits[28];
    __shared__ float red[2];

    if (t < 512) {     // reduce the 64 per-(b,p)-block partials
        float s = 0.f;
        const float* Pb = P + (size_t)b * 64 * 512 + t;
        #pragma unroll 8
        for (int c = 0; c < 64; ++c) s += Pb[c * 512];
        z[t] = s;
    } else if (t < 768) {
        z[t] = qst[b * 256 + (t - 512)];
    }
    __syncthreads();
    {   // layer 4: 768 -> 512, 2-way k-split per output
        int o = t & 511, hf = t >> 9;
        float acc = 0.f;
        const float4* Wv = (const float4*)W4v;
        const float4* z4 = (const float4*)z;
        #pragma unroll 4
        for (int kb = hf * 96; kb < hf * 96 + 96; ++kb) {
            float4 w = Wv[kb * 512 + o];
            float4 zz = z4[kb];
            acc = fmaf(w.x, zz.x, acc);
            acc = fmaf(w.y, zz.y, acc);
            acc = fmaf(w.z, zz.z, acc);
            acc = fmaf(w.w, zz.w, acc);
        }
        ps[t] = acc;
    }
    __syncthreads();
    if (t < 512) h4[t] = fmaxf(ps[t] + ps[t + 512] + b4[t], 0.f);
    __syncthreads();
    {   // layer 5: 512 -> 512, 2-way k-split per output
        int o = t & 511, hf = t >> 9;
        float acc = 0.f;
        const float4* Wv = (const float4*)W5v;
        const float4* h44 = (const float4*)h4;
        #pragma unroll 4
        for (int kb = hf * 64; kb < hf * 64 + 64; ++kb) {
            float4 w = Wv[kb * 512 + o];
            float4 hh = h44[kb];
            acc = fmaf(w.x, hh.x, acc);
            acc = fmaf(w.y, hh.y, acc);
            acc = fmaf(w.z, hh.z, acc);
            acc = fmaf(w.w, hh.w, acc);
        }
        ps[t] = acc;
    }
    __syncthreads();
    if (t < 512) h5[t] = fmaxf(ps[t] + ps[t + 512] + b5[t], 0.f);
    __syncthreads();
    {   // layer 6: 512 -> 28 (32 lanes per output)
        int o = t >> 5, c = t & 31;
        if (o < 28) {
            float acc = 0.f;
            for (int k = c; k < 512; k += 32) acc = fmaf(W6[o * 512 + k], h5[k], acc);
            acc += __shfl_xor(acc, 1);
            acc += __shfl_xor(acc, 2);
            acc += __shfl_xor(acc, 4);
            acc += __shfl_xor(acc, 8);
            acc += __shfl_xor(acc, 16);
            if (c == 0) logits[o] = acc + b6[o];
        }
    }
    __syncthreads();
    if (t == 0) {
        float mx = -1e30f;
        for (int cc = 0; cc < 28; ++cc) mx = fmaxf(mx, logits[cc]);
        float se = 0.f;
        for (int cc = 0; cc < 28; ++cc) se += expf(logits[cc] - mx);
        red[0] = mx; red[1] = logf(se);
    }
    __syncthreads();
    if (t < 28) out[b * 28 + t] = logits[t] - red[0] - red[1];
}

extern "C" void kernel_launch(void* const* d_in, const int* in_sizes, int n_in,
                              void* d_out, int out_size, void* d_ws, size_t ws_size,
                              hipStream_t stream)
{
    const float* x   = (const float*)d_in[0];
    const float* qst = (const float*)d_in[1];
    const float* W0  = (const float*)d_in[2];
    const float* b0  = (const float*)d_in[3];
    const float* W1  = (const float*)d_in[4];
    const float* b1  = (const float*)d_in[5];
    const float* W2  = (const float*)d_in[6];
    const float* b2  = (const float*)d_in[7];
    const float* W3  = (const float*)d_in[8];
    const float* b3  = (const float*)d_in[9];
    const float* W4  = (const float*)d_in[10];
    const float* b4  = (const float*)d_in[11];
    const float* W5  = (const float*)d_in[12];
    const float* b5  = (const float*)d_in[13];
    const float* W6  = (const float*)d_in[14];
    const float* b6  = (const float*)d_in[15];
    float* out = (float*)d_out;

    char* ws = (char*)d_ws;
    unsigned short* Wp  = (unsigned short*)(ws);             // 1.5 MiB
    unsigned short* W0p = (unsigned short*)(ws + 1572864);   // 64 KiB
    float*          W4v = (float*)(ws + 1638400);            // 1.5 MiB
    float*          W5v = (float*)(ws + 3211264);            // 1 MiB
    float*          P   = (float*)(ws + 4259840);            // 4 MiB partials

    k_prep <<<NPV_TOTAL / 256, 256, 0, stream>>>(W1, W2, W3, W0, W4, W5,
                                                 Wp, W0p, W4v, W5v);
    k_fused<<<2048, 512, 0, stream>>>(x, Wp, W0p, b0, b1, b2, b3, P);
    k_tail <<<32, 1024, 0, stream>>>(P, qst, W4v, b4, W5v, b5, W6, b6, out);
}

// Round 16
// 313.358 us; speedup vs baseline: 3.4326x; 1.0255x over previous
//
#include <hip/hip_runtime.h>
#include <math.h>

// Relational Network fused pipeline for MI355X (gfx950).
// B=32, D=64, K=26, QST=256, G=[512x6, 28], AGG at layer 4.
//
// Round 21 changes vs rounds 19/20:
//  - k_fused: round-19 form restored (fenced CLUSTER; round 20's A/B showed
//    fence removal is neutral-to-worse: 232.6 -> 237.0). k-loop is
//    plateaued at ~235us @ 2 waves/SIMD; pivot to periphery.
//  - k_tail SPLIT into 4 thin kernels at 8x parallelism: the old 32-block
//    k_tail used 12.5% of CUs and streamed 2.6MB/block of W4/W5 at
//    single-CU L2 bandwidth (~40-55us). Now:
//      k_t1: P-reduce -> Z       (256 blocks: (b, 64-col slice))
//      k_t2: layer 4 768->512    (256 blocks: (b, 64-out slice), 4-way k)
//      k_t3: layer 5 512->512    (256 blocks, same shape)
//      k_t4: layer 6 + logsoftmax (32 blocks, trivial)
//    W streams spread over 256 CUs -> ~1/8 wall time; graph launches ~2us.
//  - k_prep (vectorized) unchanged.

typedef __attribute__((ext_vector_type(8))) short bf16x8;   // 8 bf16 in 4 VGPRs
typedef __attribute__((ext_vector_type(4))) float f32x4;    // MFMA 16x16 accumulator
typedef __attribute__((ext_vector_type(4))) unsigned int u32x4;

__device__ __forceinline__ unsigned short f2bf(float f) {
    union { float f; unsigned u; } x; x.f = f;
    unsigned r = x.u + 0x7fffu + ((x.u >> 16) & 1u);   // RNE
    return (unsigned short)(r >> 16);
}

// ---------------- pack / transpose weights (vectorized) ----------------
// Wp layout per layer: [wave(8)][s(16)][jj(4)][lane(64)][j(8)] bf16,
//   value = W[n][k], n = (wave*4+jj)*16 + (lane&15), k = s*32 + (lane>>4)*8 + j.
// W0p: same with s(2) over padded K=64 (k >= 52 -> 0).
// W4v/W5v: fp32 [k/4][512 out][4] so tail threads stream float4.
#define NPV_WP   98304            // 3 * 512 * 64   (8 bf16/thread)
#define NPV_W0P  4096             // 512 * 8        (8 bf16/thread)
#define NPV_W4   98304            // 768*512/4      (4 f32/thread)
#define NPV_W5   65536            // 512*512/4
#define NPV_TOTAL (NPV_WP + NPV_W0P + NPV_W4 + NPV_W5)   // 266240 = 1040*256
__global__ void k_prep(const float* __restrict__ W1, const float* __restrict__ W2,
                       const float* __restrict__ W3, const float* __restrict__ W0,
                       const float* __restrict__ W4, const float* __restrict__ W5,
                       unsigned short* __restrict__ Wp,   // [3][262144] bf16
                       unsigned short* __restrict__ W0p,  // [32768] bf16
                       float* __restrict__ W4v,           // [192][512][4] fp32
                       float* __restrict__ W5v)           // [128][512][4] fp32
{
    int f = blockIdx.x * 256 + threadIdx.x;
    if (f < NPV_WP) {
        int l = f >> 15, r = f & 32767;
        int n = r >> 6, kq = r & 63;                 // k0 = kq*8
        const float* W = (l == 0) ? W1 : (l == 1) ? W2 : W3;
        const float* src = W + n * 512 + kq * 8;
        int s = kq >> 2, q4 = kq & 3;
        int wv = n >> 6, jj = (n >> 4) & 3, i16 = n & 15;
        int lane = q4 * 16 + i16;
        unsigned w[4];
        #pragma unroll
        for (int h = 0; h < 4; ++h)
            w[h] = (unsigned)f2bf(src[h * 2]) | ((unsigned)f2bf(src[h * 2 + 1]) << 16);
        *(u32x4*)(Wp + (size_t)l * 262144 + ((((wv * 16 + s) * 4 + jj) * 64 + lane) << 3))
            = (u32x4){w[0], w[1], w[2], w[3]};
    } else if (f < NPV_WP + NPV_W0P) {
        int g = f - NPV_WP;
        int n = g >> 3, kq = g & 7;
        int s = kq >> 2, q4 = kq & 3;
        int wv = n >> 6, jj = (n >> 4) & 3, i16 = n & 15;
        int lane = q4 * 16 + i16;
        unsigned w[4];
        #pragma unroll
        for (int h = 0; h < 4; ++h) {
            int k0 = kq * 8 + h * 2, k1 = k0 + 1;
            float f0 = (k0 < 52) ? W0[n * 52 + k0] : 0.f;
            float f1 = (k1 < 52) ? W0[n * 52 + k1] : 0.f;
            w[h] = (unsigned)f2bf(f0) | ((unsigned)f2bf(f1) << 16);
        }
        *(u32x4*)(W0p + ((((wv * 2 + s) * 4 + jj) * 64 + lane) << 3))
            = (u32x4){w[0], w[1], w[2], w[3]};
    } else if (f < NPV_WP + NPV_W0P + NPV_W4) {
        int g = f - (NPV_WP + NPV_W0P);
        int o = g / 192, kb = g % 192;
        float4 w = *(const float4*)(W4 + (size_t)o * 768 + kb * 4);
        *(float4*)(W4v + (size_t)kb * 2048 + o * 4) = w;
    } else {
        int g = f - (NPV_WP + NPV_W0P + NPV_W4);
        int o = g >> 7, kb = g & 127;
        float4 w = *(const float4*)(W5 + (size_t)o * 512 + kb * 4);
        *(float4*)(W5v + (size_t)kb * 2048 + o * 4) = w;
    }
}

// ---------------- h-store epilogue: bias + relu + bf16 LDS write ----
// Granule-column-major target: byte = (col>>3)*1024 + (row ^ ((col>>3)&7))*16
//                                    + (col&7)*2.
// DPP quad_perm swap on f32, then v_cvt_pk_bf16_f32 packs (col, col+1) into
// one dword; even lanes write ds_write_b32.
__device__ __forceinline__ void store_h(const f32x4 (&acc)[4][4], const float* __restrict__ bl,
                                        unsigned short* hbuf, int wave, int i16, int q4, int lane)
{
    char* base = (char*)hbuf;
    #pragma unroll
    for (int j = 0; j < 4; ++j) {
        int col = (wave * 4 + j) * 16 + i16;
        int g = col >> 3;
        int e = g & 7;
        float bb = bl[col];
        char* colbase = base + g * 1024 + ((col & 7) << 1);
        #pragma unroll
        for (int mt = 0; mt < 4; ++mt) {
            #pragma unroll
            for (int r = 0; r < 4; ++r) {
                int row = mt * 16 + q4 * 4 + r;
                float v = fmaxf(acc[mt][j][r] + bb, 0.f);
                int vi = __float_as_int(v);
                // quad_perm [1,0,3,2]: each lane gets partner (lane^1)'s f32
                int swi = __builtin_amdgcn_update_dpp(0, vi, 0xB1, 0xF, 0xF, true);
                if ((lane & 1) == 0) {
                    unsigned pk;
                    asm("v_cvt_pk_bf16_f32 %0, %1, %2" : "=v"(pk) : "v"(vi), "v"(swi));
                    int slot = row ^ e;
                    *(unsigned*)(colbase + slot * 16) = pk;
                }
            }
        }
    }
}

#define CLUSTER(AV0, AV1, AV2, AV3, BV, JJ)                                              \
    __builtin_amdgcn_s_setprio(1);                                                      \
    acc[0][JJ] = __builtin_amdgcn_mfma_f32_16x16x32_bf16(AV0, BV, acc[0][JJ], 0, 0, 0); \
    acc[1][JJ] = __builtin_amdgcn_mfma_f32_16x16x32_bf16(AV1, BV, acc[1][JJ], 0, 0, 0); \
    acc[2][JJ] = __builtin_amdgcn_mfma_f32_16x16x32_bf16(AV2, BV, acc[2][JJ], 0, 0, 0); \
    acc[3][JJ] = __builtin_amdgcn_mfma_f32_16x16x32_bf16(AV3, BV, acc[3][JJ], 0, 0, 0); \
    __builtin_amdgcn_s_setprio(0);                                                      \
    __builtin_amdgcn_sched_barrier(0);

// ---------------- fused layers 0..3 ----------------
// One block per (b,p): 64 pair-rows. h tile 64x512 bf16, DOUBLE-BUFFERED in
// LDS: layer l reads hsm[l&1], writes hsm[(l+1)&1]. Granule-column-major
// within each buffer: [g=k>>3][slot=row^(g&7)][8 shorts].
// 8 waves; wave w computes cols [w*64, w*64+64): acc = 4 (row tiles) x 4 (col tiles).
__global__ __launch_bounds__(512, 2) void k_fused(
    const float* __restrict__ x,
    const unsigned short* __restrict__ Wp,
    const unsigned short* __restrict__ W0p,
    const float* __restrict__ b0, const float* __restrict__ b1,
    const float* __restrict__ b2, const float* __restrict__ b3,
    float* __restrict__ P)
{
    __shared__ __align__(16) unsigned short hsm[2 * 64 * 512];   // 128 KiB (2 bufs)
    __shared__ __align__(16) unsigned short xs[8 * 64 * 8];      // 8 KiB (x-pair tile)
    int t = threadIdx.x;
    int blk = blockIdx.x;
    int b = blk >> 6, p = blk & 63;

    // ---- stage xs: [g(8)][slot=row^g][8] bf16 of [x[b,row,:26] | x[b,p,:26] | 0] ----
    {
        int row = t >> 3, gr = t & 7;
        const float* xq = x + (size_t)(b * 64 + row) * 26;
        const float* xp = x + (size_t)(b * 64 + p) * 26;
        unsigned w[4];
        #pragma unroll
        for (int h = 0; h < 4; ++h) {
            int k0 = gr * 8 + h * 2;
            int k1 = k0 + 1;
            float f0 = (k0 < 26) ? xq[k0] : (k0 < 52 ? xp[k0 - 26] : 0.f);
            float f1 = (k1 < 26) ? xq[k1] : (k1 < 52 ? xp[k1 - 26] : 0.f);
            w[h] = (unsigned)f2bf(f0) | ((unsigned)f2bf(f1) << 16);
        }
        *(u32x4*)((char*)xs + gr * 1024 + ((row ^ gr) << 4)) = (u32x4){w[0], w[1], w[2], w[3]};
    }

    int wave = t >> 6, lane = t & 63;
    int i16 = lane & 15, q4 = lane >> 4;

    f32x4 acc[4][4];
    bf16x8 X0, X1, X2, X3, Y0, Y1, Y2, Y3;   // B stream dbuf, live across layers

    // per-wave B base for packed weights (layer stride 262144 shorts)
    const unsigned short* Bb0base = Wp + wave * 32768 + lane * 8;

    __syncthreads();   // xs ready                                   [barrier 1]

    // ---- layer 0: h0 = relu([x_q|x_p] @ W0^T + b0), K=64 padded ----
    {
        #pragma unroll
        for (int mt = 0; mt < 4; ++mt)
            #pragma unroll
            for (int j = 0; j < 4; ++j)
                acc[mt][j] = (f32x4){0.f, 0.f, 0.f, 0.f};
        const unsigned short* Bw0 = W0p + wave * 4096 + lane * 8;
        const char* xb = (const char*)xs;
        #pragma unroll
        for (int s = 0; s < 2; ++s) {
            bf16x8 bfr[4];
            #pragma unroll
            for (int j = 0; j < 4; ++j)
                bfr[j] = *(const bf16x8*)(Bw0 + s * 2048 + j * 512);
            int g = s * 4 + q4;
            const char* A0 = xb + g * 1024 + ((i16 ^ g) << 4);
            #pragma unroll
            for (int mt = 0; mt < 4; ++mt) {
                bf16x8 a = *(const bf16x8*)(A0 + mt * 256);
                #pragma unroll
                for (int j = 0; j < 4; ++j)
                    acc[mt][j] = __builtin_amdgcn_mfma_f32_16x16x32_bf16(a, bfr[j], acc[mt][j], 0, 0, 0);
            }
        }
        // prefetch layer-1 B(0)/B(1) NOW; latency hides under store_h below
        X0 = *(const bf16x8*)(Bb0base);
        X1 = *(const bf16x8*)(Bb0base + 512);
        X2 = *(const bf16x8*)(Bb0base + 1024);
        X3 = *(const bf16x8*)(Bb0base + 1536);
        Y0 = *(const bf16x8*)(Bb0base + 2048);
        Y1 = *(const bf16x8*)(Bb0base + 2560);
        Y2 = *(const bf16x8*)(Bb0base + 3072);
        Y3 = *(const bf16x8*)(Bb0base + 3584);
        store_h(acc, b0, hsm, wave, i16, q4, lane);   // h0 -> buf0
    }
    __syncthreads();   // buf0 ready                                 [barrier 2]

    // ---- layers 1..3: X/Y B-dbuf (2-step-ahead), A even/odd dbuf (1 ahead) ----
    int A_even = (q4 << 10) + ((i16 ^ q4) << 4);
    int A_odd  = 4096 + (A_even ^ 64);

    #pragma unroll 1
    for (int l = 0; l < 3; ++l) {
        const float* bl = (l == 0) ? b1 : (l == 1) ? b2 : b3;
        const unsigned short* Bb = Bb0base + (size_t)l * 262144;
        const char* hb = (const char*)hsm + (l & 1) * 65536;   // read buffer
        const char* hbe = hb + A_even;          // even-step A base
        const char* hbo = hb + A_odd;           // odd-step A base

        #pragma unroll
        for (int mt = 0; mt < 4; ++mt)
            #pragma unroll
            for (int j = 0; j < 4; ++j)
                acc[mt][j] = (f32x4){0.f, 0.f, 0.f, 0.f};

        // A(0)
        bf16x8 aE0 = *(const bf16x8*)(hbe);
        bf16x8 aE1 = *(const bf16x8*)(hbe + 256);
        bf16x8 aE2 = *(const bf16x8*)(hbe + 512);
        bf16x8 aE3 = *(const bf16x8*)(hbe + 768);
        bf16x8 aO0, aO1, aO2, aO3;

        #pragma unroll 1
        for (int s = 0; s < 16; s += 2) {
            // ===== even step s: consume aE*, X*; reload X = B(s+2), aO = A(s+1) =====
            {
                const unsigned short* BX = Bb + ((s + 2 < 16) ? (s + 2) : 14) * 2048;
                const char* po = hbo + (s << 12);      // A(s+1)
                CLUSTER(aE0, aE1, aE2, aE3, X0, 0)
                X0 = *(const bf16x8*)(BX);
                aO0 = *(const bf16x8*)(po);
                aO1 = *(const bf16x8*)(po + 256);
                CLUSTER(aE0, aE1, aE2, aE3, X1, 1)
                X1 = *(const bf16x8*)(BX + 512);
                aO2 = *(const bf16x8*)(po + 512);
                aO3 = *(const bf16x8*)(po + 768);
                CLUSTER(aE0, aE1, aE2, aE3, X2, 2)
                X2 = *(const bf16x8*)(BX + 1024);
                CLUSTER(aE0, aE1, aE2, aE3, X3, 3)
                X3 = *(const bf16x8*)(BX + 1536);
            }
            // ===== odd step s+1: consume aO*, Y*; reload Y = B(s+3), aE = A(s+2) =====
            {
                const unsigned short* BY = Bb + ((s + 3 < 16) ? (s + 3) : 15) * 2048;
                const char* pe = hbe + ((s + 2 < 16 ? s + 2 : 14) << 12);   // A(s+2)
                CLUSTER(aO0, aO1, aO2, aO3, Y0, 0)
                Y0 = *(const bf16x8*)(BY);
                aE0 = *(const bf16x8*)(pe);
                aE1 = *(const bf16x8*)(pe + 256);
                CLUSTER(aO0, aO1, aO2, aO3, Y1, 1)
                Y1 = *(const bf16x8*)(BY + 512);
                aE2 = *(const bf16x8*)(pe + 512);
                aE3 = *(const bf16x8*)(pe + 768);
                CLUSTER(aO0, aO1, aO2, aO3, Y2, 2)
                Y2 = *(const bf16x8*)(BY + 1024);
                CLUSTER(aO0, aO1, aO2, aO3, Y3, 3)
                Y3 = *(const bf16x8*)(BY + 1536);
            }
        }

        if (l < 2) {
            // prefetch NEXT layer's B(0)/B(1) before the epilogue; its L2
            // latency hides under store_h's VALU work (tail reloads above
            // were dead and are simply overwritten here)
            const unsigned short* Bn = Bb + 262144;
            X0 = *(const bf16x8*)(Bn);
            X1 = *(const bf16x8*)(Bn + 512);
            X2 = *(const bf16x8*)(Bn + 1024);
            X3 = *(const bf16x8*)(Bn + 1536);
            Y0 = *(const bf16x8*)(Bn + 2048);
            Y1 = *(const bf16x8*)(Bn + 2560);
            Y2 = *(const bf16x8*)(Bn + 3072);
            Y3 = *(const bf16x8*)(Bn + 3584);
            // write h_{l+1} into the OTHER buffer: no read-hazard barrier needed
            store_h(acc, bl, (unsigned short*)((char*)hsm + ((l + 1) & 1) * 65536),
                    wave, i16, q4, lane);
            __syncthreads();   // next buffer ready     [barriers 3,4]
        } else {
            // layer 3: bias + relu + sum over 64 rows -> per-block partial P[blk][col]
            #pragma unroll
            for (int j = 0; j < 4; ++j) {
                int col = (wave * 4 + j) * 16 + i16;
                float bb = bl[col];
                float sum = 0.f;
                #pragma unroll
                for (int mt = 0; mt < 4; ++mt)
                    #pragma unroll
                    for (int r = 0; r < 4; ++r)
                        sum += fmaxf(acc[mt][j][r] + bb, 0.f);
                sum += __shfl_xor(sum, 16);
                sum += __shfl_xor(sum, 32);
                if (q4 == 0) P[(size_t)blk * 512 + col] = sum;
            }
        }
    }
}

// ---------------- tail stage 1: reduce P over the 64 p-blocks -> Z ----
__global__ __launch_bounds__(64) void k_t1(const float* __restrict__ P,
                                           float* __restrict__ Z)
{
    int b = blockIdx.x >> 3, sl = blockIdx.x & 7;
    int col = sl * 64 + threadIdx.x;
    const float* Pb = P + (size_t)b * 64 * 512 + col;
    float s = 0.f;
    #pragma unroll 8
    for (int c = 0; c < 64; ++c) s += Pb[c * 512];
    Z[b * 512 + col] = s;
}

// ---------------- tail stage 2: layer 4 (768 -> 512), relu -> H4 ----
// Grid (32 b x 8 slices); each block: 64 outputs, 4-way k-split over 192 kb.
__global__ __launch_bounds__(256) void k_t2(
    const float* __restrict__ Z, const float* __restrict__ qst,
    const float* __restrict__ W4v, const float* __restrict__ b4,
    float* __restrict__ H4)
{
    int b = blockIdx.x >> 3, sl = blockIdx.x & 7;
    int t = threadIdx.x;
    __shared__ __align__(16) float z[768];
    __shared__ float ps[256];
    for (int i = t; i < 768; i += 256)
        z[i] = (i < 512) ? Z[b * 512 + i] : qst[b * 256 + (i - 512)];
    __syncthreads();
    int o = sl * 64 + (t & 63), hf = t >> 6;   // hf in [0,4)
    float acc = 0.f;
    const float4* Wv = (const float4*)W4v;
    const float4* z4 = (const float4*)z;
    #pragma unroll 4
    for (int kb = hf * 48; kb < hf * 48 + 48; ++kb) {
        float4 w = Wv[kb * 512 + o];
        float4 zz = z4[kb];
        acc = fmaf(w.x, zz.x, acc);
        acc = fmaf(w.y, zz.y, acc);
        acc = fmaf(w.z, zz.z, acc);
        acc = fmaf(w.w, zz.w, acc);
    }
    ps[t] = acc;
    __syncthreads();
    if (t < 64)
        H4[b * 512 + o] = fmaxf(ps[t] + ps[t + 64] + ps[t + 128] + ps[t + 192] + b4[o], 0.f);
}

// ---------------- tail stage 3: layer 5 (512 -> 512), relu -> H5 ----
__global__ __launch_bounds__(256) void k_t3(
    const float* __restrict__ H4,
    const float* __restrict__ W5v, const float* __restrict__ b5,
    float* __restrict__ H5)
{
    int b = blockIdx.x >> 3, sl = blockIdx.x & 7;
    int t = threadIdx.x;
    __shared__ __align__(16) float h4[512];
    __shared__ float ps[256];
    for (int i = t; i < 512; i += 256) h4[i] = H4[b * 512 + i];
    __syncthreads();
    int o = sl * 64 + (t & 63), hf = t >> 6;   // hf in [0,4)
    float acc = 0.f;
    const float4* Wv = (const float4*)W5v;
    const float4* h44 = (const float4*)h4;
    #pragma unroll 4
    for (int kb = hf * 32; kb < hf * 32 + 32; ++kb) {
        float4 w = Wv[kb * 512 + o];
        float4 hh = h44[kb];
        acc = fmaf(w.x, hh.x, acc);
        acc = fmaf(w.y, hh.y, acc);
        acc = fmaf(w.z, hh.z, acc);
        acc = fmaf(w.w, hh.w, acc);
    }
    ps[t] = acc;
    __syncthreads();
    if (t < 64)
        H5[b * 512 + o] = fmaxf(ps[t] + ps[t + 64] + ps[t + 128] + ps[t + 192] + b5[o], 0.f);
}

// ---------------- tail stage 4: layer 6 (512 -> 28) + log_softmax ----
__global__ __launch_bounds__(512) void k_t4(
    const float* __restrict__ H5,
    const float* __restrict__ W6, const float* __restrict__ b6,
    float* __restrict__ out)
{
    int b = blockIdx.x, t = threadIdx.x;
    __shared__ __align__(16) float h5[512];
    __shared__ float logits[28];
    __shared__ float red[2];
    h5[t] = H5[b * 512 + t];
    __syncthreads();
    {   // 16 lanes per output
        int o = t >> 4, c = t & 15;
        if (o < 28) {
            float acc = 0.f;
            for (int k = c; k < 512; k += 16) acc = fmaf(W6[o * 512 + k], h5[k], acc);
            acc += __shfl_xor(acc, 1);
            acc += __shfl_xor(acc, 2);
            acc += __shfl_xor(acc, 4);
            acc += __shfl_xor(acc, 8);
            if (c == 0) logits[o] = acc + b6[o];
        }
    }
    __syncthreads();
    if (t == 0) {
        float mx = -1e30f;
        for (int cc = 0; cc < 28; ++cc) mx = fmaxf(mx, logits[cc]);
        float se = 0.f;
        for (int cc = 0; cc < 28; ++cc) se += expf(logits[cc] - mx);
        red[0] = mx; red[1] = logf(se);
    }
    __syncthreads();
    if (t < 28) out[b * 28 + t] = logits[t] - red[0] - red[1];
}

extern "C" void kernel_launch(void* const* d_in, const int* in_sizes, int n_in,
                              void* d_out, int out_size, void* d_ws, size_t ws_size,
                              hipStream_t stream)
{
    const float* x   = (const float*)d_in[0];
    const float* qst = (const float*)d_in[1];
    const float* W0  = (const float*)d_in[2];
    const float* b0  = (const float*)d_in[3];
    const float* W1  = (const float*)d_in[4];
    const float* b1  = (const float*)d_in[5];
    const float* W2  = (const float*)d_in[6];
    const float* b2  = (const float*)d_in[7];
    const float* W3  = (const float*)d_in[8];
    const float* b3  = (const float*)d_in[9];
    const float* W4  = (const float*)d_in[10];
    const float* b4  = (const float*)d_in[11];
    const float* W5  = (const float*)d_in[12];
    const float* b5  = (const float*)d_in[13];
    const float* W6  = (const float*)d_in[14];
    const float* b6  = (const float*)d_in[15];
    float* out = (float*)d_out;

    char* ws = (char*)d_ws;
    unsigned short* Wp  = (unsigned short*)(ws);             // 1.5 MiB
    unsigned short* W0p = (unsigned short*)(ws + 1572864);   // 64 KiB
    float*          W4v = (float*)(ws + 1638400);            // 1.5 MiB
    float*          W5v = (float*)(ws + 3211264);            // 1 MiB
    float*          P   = (float*)(ws + 4259840);            // 4 MiB partials
    float*          Z   = (float*)(ws + 8454144);            // 64 KiB
    float*          H4  = (float*)(ws + 8519680);            // 64 KiB
    float*          H5  = (float*)(ws + 8585216);            // 64 KiB

    k_prep <<<NPV_TOTAL / 256, 256, 0, stream>>>(W1, W2, W3, W0, W4, W5,
                                                 Wp, W0p, W4v, W5v);
    k_fused<<<2048, 512, 0, stream>>>(x, Wp, W0p, b0, b1, b2, b3, P);
    k_t1   <<<256, 64, 0, stream>>>(P, Z);
    k_t2   <<<256, 256, 0, stream>>>(Z, qst, W4v, b4, H4);
    k_t3   <<<256, 256, 0, stream>>>(H4, W5v, b5, H5);
    k_t4   <<<32, 512, 0, stream>>>(H5, W6, b6, out);
}